// Round 3
// baseline (129.923 us; speedup 1.0000x reference)
//
#include <hip/hip_runtime.h>
#include <stdint.h>

#define B_  2048
#define D_  1024
#define F_  1024
#define S_  64
#define R_  16

typedef __attribute__((ext_vector_type(8))) short  s16x8;
typedef __attribute__((ext_vector_type(4))) unsigned short u16x4;
typedef __attribute__((ext_vector_type(8))) unsigned short u16x8;
typedef __attribute__((ext_vector_type(4))) float  f32x4;

__device__ __forceinline__ unsigned short f2b(float f){
  unsigned u = __float_as_uint(f);
  u = u + 0x7fffu + ((u >> 16) & 1u);   // RNE to bf16
  return (unsigned short)(u >> 16);
}
__device__ __forceinline__ float b2f(unsigned short s){
  return __uint_as_float(((unsigned)s) << 16);
}

__device__ __forceinline__ void gload16(const void* g, void* l){
  __builtin_amdgcn_global_load_lds((const __attribute__((address_space(1))) unsigned int*)g,
                                   (__attribute__((address_space(3))) unsigned int*)l, 16, 0, 0);
}

// ---------------- kernel 1a: XC = [bf16(x) | bf16(carry)]  (B x 2048) ----------------
__global__ void cast_xc_kernel(const float* __restrict__ x, const float* __restrict__ carry,
                               unsigned short* __restrict__ XC){
  int i = blockIdx.x * blockDim.x + threadIdx.x;
  if (i >= B_ * (D_/4)) return;
  int b = i >> 8;
  int j = (i & 255) * 4;
  float4 xv = *(const float4*)&x[(size_t)b*D_ + j];
  float4 cv = *(const float4*)&carry[(size_t)b*F_ + j];
  u16x4 xs, cs;
  xs[0]=f2b(xv.x); xs[1]=f2b(xv.y); xs[2]=f2b(xv.z); xs[3]=f2b(xv.w);
  cs[0]=f2b(cv.x); cs[1]=f2b(cv.y); cs[2]=f2b(cv.z); cs[3]=f2b(cv.w);
  *(u16x4*)&XC[(size_t)b*2048 + j]        = xs;
  *(u16x4*)&XC[(size_t)b*2048 + 1024 + j] = cs;
}

// ---------------- kernel 1b: transpose-cast 6 weights into Wt_all[u][n][k] bf16 -----------
// unit order: 0=ir(x), 1=rr(c), 2=iu(x), 3=ru(c), 4=ic(x), 5=rc(c)
__global__ void wcast_kernel(const float* __restrict__ w_ir, const float* __restrict__ w_rr,
                             const float* __restrict__ w_iu, const float* __restrict__ w_ru,
                             const float* __restrict__ w_ic, const float* __restrict__ w_rc,
                             unsigned short* __restrict__ Wt_all){
  int u = blockIdx.y;
  const float* W;
  switch(u){ case 0: W=w_ir; break; case 1: W=w_rr; break; case 2: W=w_iu; break;
             case 3: W=w_ru; break; case 4: W=w_ic; break; default: W=w_rc; break; }
  unsigned short* O = Wt_all + (size_t)u * (1024*1024);
  __shared__ unsigned short T[64][72];   // row stride 144B (9*16B)
  int t = threadIdx.x;
  int n0 = (blockIdx.x & 15) * 64;
  int k0 = (blockIdx.x >> 4) * 64;
  int c4 = (t & 15) * 4;
  int kk = t >> 4;
  #pragma unroll
  for (int i = 0; i < 4; i++){
    int k = kk + i*16;
    float4 v = *(const float4*)&W[(size_t)(k0+k)*F_ + n0 + c4];
    T[c4+0][k] = f2b(v.x); T[c4+1][k] = f2b(v.y); T[c4+2][k] = f2b(v.z); T[c4+3][k] = f2b(v.w);
  }
  __syncthreads();
  int n = t >> 2, ch = (t & 3) * 16;
  u16x8 a = *(const u16x8*)&T[n][ch];
  u16x8 b = *(const u16x8*)&T[n][ch+8];
  *(u16x8*)&O[(size_t)(n0+n)*1024 + k0 + ch]     = a;
  *(u16x8*)&O[(size_t)(n0+n)*1024 + k0 + ch + 8] = b;
}

// ---------------- kernel 2: bucket examples by adapter id ----------------
__global__ void bucket_kernel(const int* __restrict__ ids, int* __restrict__ starts,
                              int* __restrict__ order){
  __shared__ int cnt[S_]; __shared__ int off[S_+1]; __shared__ int cur[S_];
  int t = threadIdx.x;
  if (t < S_) cnt[t] = 0;
  __syncthreads();
  for (int b = t; b < B_; b += 256) atomicAdd(&cnt[ids[b]], 1);
  __syncthreads();
  if (t == 0){ off[0] = 0; for (int s2 = 0; s2 < S_; s2++) off[s2+1] = off[s2] + cnt[s2]; }
  __syncthreads();
  if (t < S_) cur[t] = off[t];
  __syncthreads();
  for (int b = t; b < B_; b += 256){ int p = atomicAdd(&cur[ids[b]], 1); order[p] = b; }
  if (t < S_+1) starts[t] = off[t];
}

// ---------------- kernel 3: low[g][b][r] = XC[b, gslice] . la_g[id[b]][:,r]  (MFMA) ------
__global__ __launch_bounds__(256) void low_kernel(
    const unsigned short* __restrict__ XC,
    const float* __restrict__ la_ir, const float* __restrict__ la_iu,
    const float* __restrict__ la_ic, const float* __restrict__ la_rr,
    const float* __restrict__ la_ru, const float* __restrict__ la_rc,
    const int* __restrict__ starts, const int* __restrict__ order,
    float* __restrict__ low){
  int s = blockIdx.x, g = blockIdx.y;
  const float* la;
  switch(g){ case 0: la=la_ir; break; case 1: la=la_iu; break; case 2: la=la_ic; break;
             case 3: la=la_rr; break; case 4: la=la_ru; break; default: la=la_rc; break; }
  int kofs = (g < 3) ? 0 : 1024;
  la += (size_t)s * D_ * R_;
  __shared__ unsigned short LA[16 * 1032];   // [r][d], pad 8
  int t = threadIdx.x;
  for (int i4 = t; i4 < D_*R_/4; i4 += 256){
    float4 v = *(const float4*)&la[i4*4];
    int d = i4 >> 2, r0 = (i4 & 3) * 4;
    LA[(r0+0)*1032 + d] = f2b(v.x);
    LA[(r0+1)*1032 + d] = f2b(v.y);
    LA[(r0+2)*1032 + d] = f2b(v.z);
    LA[(r0+3)*1032 + d] = f2b(v.w);
  }
  __syncthreads();
  int start = starts[s], cnt = starts[s+1] - start;
  if (cnt == 0) return;
  int lane = t & 63, wave = t >> 6;
  int l15 = lane & 15, kq = (lane >> 4) * 8;
  int ntiles = (cnt + 15) >> 4;
  for (int mt = wave*2; mt < ntiles; mt += 8){
    bool two = (mt + 1 < ntiles);
    int m0 = mt*16 + l15;       if (m0 >= cnt) m0 = cnt - 1;
    int m1 = (mt+1)*16 + l15;   if (m1 >= cnt) m1 = cnt - 1;
    int e0 = order[start + m0];
    int e1 = two ? order[start + m1] : e0;
    const unsigned short* A0 = XC + (size_t)e0*2048 + kofs + kq;
    const unsigned short* A1 = XC + (size_t)e1*2048 + kofs + kq;
    const unsigned short* Bp = &LA[l15*1032 + kq];
    f32x4 acc0 = {}, acc1 = {};
    #pragma unroll 4
    for (int kt = 0; kt < 1024; kt += 32){
      s16x8 a0 = *(const s16x8*)(A0 + kt);
      s16x8 a1 = *(const s16x8*)(A1 + kt);
      s16x8 b  = *(const s16x8*)(Bp + kt);
      acc0 = __builtin_amdgcn_mfma_f32_16x16x32_bf16(a0, b, acc0, 0, 0, 0);
      acc1 = __builtin_amdgcn_mfma_f32_16x16x32_bf16(a1, b, acc1, 0, 0, 0);
    }
    int rowb = (lane >> 4) * 4;
    #pragma unroll
    for (int i = 0; i < 4; i++){
      int m = mt*16 + rowb + i;
      if (m < cnt){
        int e = order[start + m];
        low[((size_t)g*B_ + e)*R_ + l15] = acc0[i];
      }
    }
    if (two){
      #pragma unroll
      for (int i = 0; i < 4; i++){
        int m = (mt+1)*16 + rowb + i;
        if (m < cnt){
          int e = order[start + m];
          low[((size_t)g*B_ + e)*R_ + l15] = acc1[i];
        }
      }
    }
  }
}

// ---------------- kernel 4: MFMA GEMM (6 uniform units, 2-phase dbuf prefetch) ------------
// Y[u] = XC[:, half(u)] @ Wt[u]^T ; u even -> x half, u odd -> carry half
__global__ __launch_bounds__(256, 3) void gemm_kernel(
    const unsigned short* __restrict__ XC,
    const unsigned short* __restrict__ Wt_all,
    float* __restrict__ Yall){
  int u = blockIdx.y;
  const unsigned short* Wt = Wt_all + (size_t)u * (1024*1024);
  float* Y = Yall + (size_t)u * ((size_t)B_ * F_);
  int kofs = (u & 1) << 10;

  __shared__ unsigned short As[2][128*32];
  __shared__ unsigned short Bs[2][128*32];

  int t = threadIdx.x;
  int lane = t & 63, wave = t >> 6;
  int mt = blockIdx.x >> 3, nt = blockIdx.x & 7;
  int row0 = mt * 128, col0 = nt * 128;
  int wrow = (wave >> 1) * 64, wcol = (wave & 1) * 64;

  int arow = t >> 2;
  int achk = (t & 3) * 8;

  const unsigned short* Ab  = XC + (size_t)(row0 + arow) * 2048 + kofs + achk;
  const unsigned short* Ab2 = Ab + (size_t)64 * 2048;
  const unsigned short* Bb  = Wt + (size_t)(col0 + arow) * 1024 + achk;
  const unsigned short* Bb2 = Bb + (size_t)64 * 1024;

  int l15 = lane & 15, kof = (lane >> 4) * 8;
  f32x4 acc[4][4] = {};

  // prologue: stage tile 0
  gload16(Ab,  &As[0][t*8]);  gload16(Ab2, &As[0][2048 + t*8]);
  gload16(Bb,  &Bs[0][t*8]);  gload16(Bb2, &Bs[0][2048 + t*8]);
  __syncthreads();

  int cur = 0;
  for (int kt = 32; kt < 1024; kt += 32){
    int nxt = cur ^ 1;
    // issue next-tile stage FIRST (overlaps with this tile's ds_read+MFMA)
    gload16(Ab  + kt, &As[nxt][t*8]);  gload16(Ab2 + kt, &As[nxt][2048 + t*8]);
    gload16(Bb  + kt, &Bs[nxt][t*8]);  gload16(Bb2 + kt, &Bs[nxt][2048 + t*8]);
    s16x8 af[4], bfr[4];
    #pragma unroll
    for (int m = 0; m < 4; m++)
      af[m] = *(const s16x8*)&As[cur][(wrow + m*16 + l15)*32 + kof];
    #pragma unroll
    for (int n = 0; n < 4; n++)
      bfr[n] = *(const s16x8*)&Bs[cur][(wcol + n*16 + l15)*32 + kof];
    #pragma unroll
    for (int m = 0; m < 4; m++){
      #pragma unroll
      for (int n = 0; n < 4; n++){
        acc[m][n] = __builtin_amdgcn_mfma_f32_16x16x32_bf16(af[m], bfr[n], acc[m][n], 0, 0, 0);
      }
    }
    __syncthreads();   // vmcnt(0)+lgkmcnt(0)+barrier: next tile staged, cur fully consumed
    cur = nxt;
  }
  // last tile
  {
    s16x8 af[4], bfr[4];
    #pragma unroll
    for (int m = 0; m < 4; m++)
      af[m] = *(const s16x8*)&As[cur][(wrow + m*16 + l15)*32 + kof];
    #pragma unroll
    for (int n = 0; n < 4; n++)
      bfr[n] = *(const s16x8*)&Bs[cur][(wcol + n*16 + l15)*32 + kof];
    #pragma unroll
    for (int m = 0; m < 4; m++){
      #pragma unroll
      for (int n = 0; n < 4; n++){
        acc[m][n] = __builtin_amdgcn_mfma_f32_16x16x32_bf16(af[m], bfr[n], acc[m][n], 0, 0, 0);
      }
    }
  }

  int orow = row0 + wrow + (lane >> 4) * 4;
  int ocol = col0 + wcol + l15;
  #pragma unroll
  for (int m = 0; m < 4; m++){
    #pragma unroll
    for (int n = 0; n < 4; n++){
      #pragma unroll
      for (int i = 0; i < 4; i++){
        Y[(size_t)(orow + m*16 + i) * F_ + ocol + n*16] = acc[m][n][i];
      }
    }
  }
}

// ---------------- kernel 5: fused delta + gates + output (bucketed) ----------------
// grid (64 ids, 8 col-tiles of 128); lb staged f32 in LDS, low staged per 32-example chunk.
__global__ __launch_bounds__(256) void final_kernel(
    const float* __restrict__ carry,
    const float* __restrict__ bias_ir, const float* __restrict__ bias_iu,
    const float* __restrict__ bias_ic,
    const float* __restrict__ lb_ir, const float* __restrict__ lb_rr,
    const float* __restrict__ lb_iu, const float* __restrict__ lb_ru,
    const float* __restrict__ lb_ic, const float* __restrict__ lb_rc,
    const int* __restrict__ starts, const int* __restrict__ order,
    const float* __restrict__ low, const float* __restrict__ Yall,
    float* __restrict__ out){
  int s = blockIdx.x;
  int c0 = blockIdx.y * 128;
  __shared__ float LBf[6 * 16 * 128];   // 48 KB  [j][r][c]
  __shared__ float LOW[32 * 96];        // 12 KB  [mi][goff+r]
  int t = threadIdx.x;

  // stage lb (j order: 0=ir,1=rr,2=iu,3=ru,4=ic,5=rc; LOW offsets per low's g: ir0 rr48 iu16 ru64 ic32 rc80)
  const float* lbp[6] = {lb_ir, lb_rr, lb_iu, lb_ru, lb_ic, lb_rc};
  #pragma unroll
  for (int j = 0; j < 6; j++){
    const float* lb = lbp[j] + (size_t)s * R_ * F_;
    #pragma unroll
    for (int i4 = 0; i4 < 2; i4++){
      int idx = t + i4*256;          // 512 float4 per group
      int r = idx >> 5, c4 = (idx & 31) << 2;
      float4 v = *(const float4*)&lb[(size_t)r*F_ + c0 + c4];
      *(float4*)&LBf[j*2048 + r*128 + c4] = v;
    }
  }
  __syncthreads();

  int start = starts[s], cnt = starts[s+1] - start;
  int cl = (t & 31) * 4, ml = t >> 5;
  float4 br4 = *(const float4*)&bias_ir[c0 + cl];
  float4 bu4 = *(const float4*)&bias_iu[c0 + cl];
  float4 bc4 = *(const float4*)&bias_ic[c0 + cl];

  for (int m0 = 0; m0 < cnt; m0 += 32){
    int mc = cnt - m0; if (mc > 32) mc = 32;
    if (m0) __syncthreads();
    // stage low chunk: mc examples x 96 floats (= mc*24 float4)
    for (int i4 = t; i4 < mc*24; i4 += 256){
      int mi = i4 / 24, q = i4 - mi*24;
      int g = q >> 2, r4 = (q & 3) << 2;
      int b = order[start + m0 + mi];
      float4 v = *(const float4*)&low[((size_t)g*B_ + b)*R_ + r4];
      *(float4*)&LOW[mi*96 + g*16 + r4] = v;
    }
    __syncthreads();
    for (int mi = ml; mi < mc; mi += 8){
      int b = order[start + m0 + mi];
      size_t idx = (size_t)b * F_ + c0 + cl;
      float4 yri = *(const float4*)&Yall[0*(size_t)B_*F_ + idx];
      float4 yrr = *(const float4*)&Yall[1*(size_t)B_*F_ + idx];
      float4 yui = *(const float4*)&Yall[2*(size_t)B_*F_ + idx];
      float4 yur = *(const float4*)&Yall[3*(size_t)B_*F_ + idx];
      float4 yci = *(const float4*)&Yall[4*(size_t)B_*F_ + idx];
      float4 ycr = *(const float4*)&Yall[5*(size_t)B_*F_ + idx];
      float4 cv  = *(const float4*)&carry[idx];
      f32x4 dr = {}, du = {}, dic = {}, drc = {};
      const float* lw = &LOW[mi*96];
      #pragma unroll
      for (int r = 0; r < 16; r++){
        f32x4 w;
        w = *(const f32x4*)&LBf[0*2048 + r*128 + cl]; dr  += lw[0  + r] * w;
        w = *(const f32x4*)&LBf[1*2048 + r*128 + cl]; dr  += lw[48 + r] * w;
        w = *(const f32x4*)&LBf[2*2048 + r*128 + cl]; du  += lw[16 + r] * w;
        w = *(const f32x4*)&LBf[3*2048 + r*128 + cl]; du  += lw[64 + r] * w;
        w = *(const f32x4*)&LBf[4*2048 + r*128 + cl]; dic += lw[32 + r] * w;
        w = *(const f32x4*)&LBf[5*2048 + r*128 + cl]; drc += lw[80 + r] * w;
      }
      float4 o;
      {
        float zr, zu, zic, zrc, rr, uu, cand;
        zr = yri.x + yrr.x + br4.x + dr[0];  rr = 1.f/(1.f+__expf(-zr));
        zu = yui.x + yur.x + bu4.x + du[0];  uu = 1.f/(1.f+__expf(-zu));
        zic = yci.x + bc4.x + dic[0];  zrc = ycr.x + drc[0];
        { float a = zic + rr*zrc; float e = __expf(-2.f*fabsf(a));
          cand = copysignf((1.f-e)/(1.f+e), a); }
        o.x = (1.f-uu)*cand + uu*cv.x;
        zr = yri.y + yrr.y + br4.y + dr[1];  rr = 1.f/(1.f+__expf(-zr));
        zu = yui.y + yur.y + bu4.y + du[1];  uu = 1.f/(1.f+__expf(-zu));
        zic = yci.y + bc4.y + dic[1];  zrc = ycr.y + drc[1];
        { float a = zic + rr*zrc; float e = __expf(-2.f*fabsf(a));
          cand = copysignf((1.f-e)/(1.f+e), a); }
        o.y = (1.f-uu)*cand + uu*cv.y;
        zr = yri.z + yrr.z + br4.z + dr[2];  rr = 1.f/(1.f+__expf(-zr));
        zu = yui.z + yur.z + bu4.z + du[2];  uu = 1.f/(1.f+__expf(-zu));
        zic = yci.z + bc4.z + dic[2];  zrc = ycr.z + drc[2];
        { float a = zic + rr*zrc; float e = __expf(-2.f*fabsf(a));
          cand = copysignf((1.f-e)/(1.f+e), a); }
        o.z = (1.f-uu)*cand + uu*cv.z;
        zr = yri.w + yrr.w + br4.w + dr[3];  rr = 1.f/(1.f+__expf(-zr));
        zu = yui.w + yur.w + bu4.w + du[3];  uu = 1.f/(1.f+__expf(-zu));
        zic = yci.w + bc4.w + dic[3];  zrc = ycr.w + drc[3];
        { float a = zic + rr*zrc; float e = __expf(-2.f*fabsf(a));
          cand = copysignf((1.f-e)/(1.f+e), a); }
        o.w = (1.f-uu)*cand + uu*cv.w;
      }
      *(float4*)&out[idx] = o;
    }
  }
}

extern "C" void kernel_launch(void* const* d_in, const int* in_sizes, int n_in,
                              void* d_out, int out_size, void* d_ws, size_t ws_size,
                              hipStream_t stream){
  const float* carry   = (const float*)d_in[0];
  const float* x       = (const float*)d_in[1];
  const int*   ids     = (const int*)d_in[2];
  const float* w_ir    = (const float*)d_in[3];
  const float* bias_ir = (const float*)d_in[4];
  const float* la_ir   = (const float*)d_in[5];
  const float* lb_ir   = (const float*)d_in[6];
  const float* w_iu    = (const float*)d_in[7];
  const float* bias_iu = (const float*)d_in[8];
  const float* la_iu   = (const float*)d_in[9];
  const float* lb_iu   = (const float*)d_in[10];
  const float* w_ic    = (const float*)d_in[11];
  const float* bias_ic = (const float*)d_in[12];
  const float* la_ic   = (const float*)d_in[13];
  const float* lb_ic   = (const float*)d_in[14];
  const float* w_rr    = (const float*)d_in[15];
  const float* la_rr   = (const float*)d_in[16];
  const float* lb_rr   = (const float*)d_in[17];
  const float* w_ru    = (const float*)d_in[18];
  const float* la_ru   = (const float*)d_in[19];
  const float* lb_ru   = (const float*)d_in[20];
  const float* w_rc    = (const float*)d_in[21];
  const float* la_rc   = (const float*)d_in[22];
  const float* lb_rc   = (const float*)d_in[23];

  char* ws = (char*)d_ws;
  unsigned short* XC     = (unsigned short*)(ws + 0);          // 8 MiB
  unsigned short* Wt_all = (unsigned short*)(ws + 8388608);    // 12 MiB (6 x 2 MiB)
  float* Yall = (float*)(ws + 20971520);                       // 48 MiB (6 x 8 MiB)
  float* low  = (float*)(ws + 71303168);                       // 768 KiB
  int* starts = (int*)(ws + 72089600);
  int* order  = (int*)(ws + 72090624);

  cast_xc_kernel<<<dim3(2048), dim3(256), 0, stream>>>(x, carry, XC);
  wcast_kernel<<<dim3(256, 6), dim3(256), 0, stream>>>(w_ir, w_rr, w_iu, w_ru, w_ic, w_rc,
                                                       Wt_all);
  bucket_kernel<<<dim3(1), dim3(256), 0, stream>>>(ids, starts, order);
  low_kernel<<<dim3(64, 6), dim3(256), 0, stream>>>(XC, la_ir, la_iu, la_ic,
                                                    la_rr, la_ru, la_rc, starts, order, low);
  gemm_kernel<<<dim3(128, 6), dim3(256), 0, stream>>>(XC, Wt_all, Yall);
  final_kernel<<<dim3(64, 8), dim3(256), 0, stream>>>(carry, bias_ir, bias_iu, bias_ic,
                                                      lb_ir, lb_rr, lb_iu, lb_ru, lb_ic, lb_rc,
                                                      starts, order, low, Yall, (float*)d_out);
}

// Round 4
// 111.539 us; speedup vs baseline: 1.1648x; 1.1648x over previous
//
#include <hip/hip_runtime.h>
#include <stdint.h>

#define B_  2048
#define D_  1024
#define F_  1024
#define S_  64
#define R_  16

typedef __attribute__((ext_vector_type(8))) short  s16x8;
typedef __attribute__((ext_vector_type(4))) unsigned short u16x4;
typedef __attribute__((ext_vector_type(8))) unsigned short u16x8;
typedef __attribute__((ext_vector_type(4))) float  f32x4;

__device__ __forceinline__ unsigned short f2b(float f){
  unsigned u = __float_as_uint(f);
  u = u + 0x7fffu + ((u >> 16) & 1u);   // RNE to bf16
  return (unsigned short)(u >> 16);
}
__device__ __forceinline__ float b2f(unsigned short s){
  return __uint_as_float(((unsigned)s) << 16);
}

__device__ __forceinline__ void gload16(const void* g, void* l){
  __builtin_amdgcn_global_load_lds((const __attribute__((address_space(1))) unsigned int*)g,
                                   (__attribute__((address_space(3))) unsigned int*)l, 16, 0, 0);
}

// ---------------- kernel 1a: XC = [bf16(x) | bf16(carry)]  (B x 2048) ----------------
__global__ void cast_xc_kernel(const float* __restrict__ x, const float* __restrict__ carry,
                               unsigned short* __restrict__ XC){
  int i = blockIdx.x * blockDim.x + threadIdx.x;
  if (i >= B_ * (D_/4)) return;
  int b = i >> 8;
  int j = (i & 255) * 4;
  float4 xv = *(const float4*)&x[(size_t)b*D_ + j];
  float4 cv = *(const float4*)&carry[(size_t)b*F_ + j];
  u16x4 xs, cs;
  xs[0]=f2b(xv.x); xs[1]=f2b(xv.y); xs[2]=f2b(xv.z); xs[3]=f2b(xv.w);
  cs[0]=f2b(cv.x); cs[1]=f2b(cv.y); cs[2]=f2b(cv.z); cs[3]=f2b(cv.w);
  *(u16x4*)&XC[(size_t)b*2048 + j]        = xs;
  *(u16x4*)&XC[(size_t)b*2048 + 1024 + j] = cs;
}

// ---------------- kernel 1b: transpose-cast 6 weights into Wt_all[u][n][k] bf16 -----------
// unit order: 0=ir(x), 1=rr(c), 2=iu(x), 3=ru(c), 4=ic(x), 5=rc(c)
__global__ void wcast_kernel(const float* __restrict__ w_ir, const float* __restrict__ w_rr,
                             const float* __restrict__ w_iu, const float* __restrict__ w_ru,
                             const float* __restrict__ w_ic, const float* __restrict__ w_rc,
                             unsigned short* __restrict__ Wt_all){
  int u = blockIdx.y;
  const float* W;
  switch(u){ case 0: W=w_ir; break; case 1: W=w_rr; break; case 2: W=w_iu; break;
             case 3: W=w_ru; break; case 4: W=w_ic; break; default: W=w_rc; break; }
  unsigned short* O = Wt_all + (size_t)u * (1024*1024);
  __shared__ unsigned short T[64][72];   // row stride 144B (9*16B)
  int t = threadIdx.x;
  int n0 = (blockIdx.x & 15) * 64;
  int k0 = (blockIdx.x >> 4) * 64;
  int c4 = (t & 15) * 4;
  int kk = t >> 4;
  #pragma unroll
  for (int i = 0; i < 4; i++){
    int k = kk + i*16;
    float4 v = *(const float4*)&W[(size_t)(k0+k)*F_ + n0 + c4];
    T[c4+0][k] = f2b(v.x); T[c4+1][k] = f2b(v.y); T[c4+2][k] = f2b(v.z); T[c4+3][k] = f2b(v.w);
  }
  __syncthreads();
  int n = t >> 2, ch = (t & 3) * 16;
  u16x8 a = *(const u16x8*)&T[n][ch];
  u16x8 b = *(const u16x8*)&T[n][ch+8];
  *(u16x8*)&O[(size_t)(n0+n)*1024 + k0 + ch]     = a;
  *(u16x8*)&O[(size_t)(n0+n)*1024 + k0 + ch + 8] = b;
}

// ---------------- kernel 2: bucket examples by adapter id ----------------
__global__ void bucket_kernel(const int* __restrict__ ids, int* __restrict__ starts,
                              int* __restrict__ order){
  __shared__ int cnt[S_]; __shared__ int off[S_+1]; __shared__ int cur[S_];
  int t = threadIdx.x;
  if (t < S_) cnt[t] = 0;
  __syncthreads();
  for (int b = t; b < B_; b += 256) atomicAdd(&cnt[ids[b]], 1);
  __syncthreads();
  if (t == 0){ off[0] = 0; for (int s2 = 0; s2 < S_; s2++) off[s2+1] = off[s2] + cnt[s2]; }
  __syncthreads();
  if (t < S_) cur[t] = off[t];
  __syncthreads();
  for (int b = t; b < B_; b += 256){ int p = atomicAdd(&cur[ids[b]], 1); order[p] = b; }
  if (t < S_+1) starts[t] = off[t];
}

// ---------------- kernel 3: low[g][b][r] = XC[b, gslice] . la_g[id[b]][:,r]  (MFMA) ------
// g order: 0=ir, 1=iu, 2=ic, 3=rr, 4=ru, 5=rc
__global__ __launch_bounds__(256) void low_kernel(
    const unsigned short* __restrict__ XC,
    const float* __restrict__ la_ir, const float* __restrict__ la_iu,
    const float* __restrict__ la_ic, const float* __restrict__ la_rr,
    const float* __restrict__ la_ru, const float* __restrict__ la_rc,
    const int* __restrict__ starts, const int* __restrict__ order,
    float* __restrict__ low){
  int s = blockIdx.x, g = blockIdx.y;
  const float* la;
  switch(g){ case 0: la=la_ir; break; case 1: la=la_iu; break; case 2: la=la_ic; break;
             case 3: la=la_rr; break; case 4: la=la_ru; break; default: la=la_rc; break; }
  int kofs = (g < 3) ? 0 : 1024;
  la += (size_t)s * D_ * R_;
  __shared__ unsigned short LA[16 * 1032];   // [r][d], pad 8
  int t = threadIdx.x;
  for (int i4 = t; i4 < D_*R_/4; i4 += 256){
    float4 v = *(const float4*)&la[i4*4];
    int d = i4 >> 2, r0 = (i4 & 3) * 4;
    LA[(r0+0)*1032 + d] = f2b(v.x);
    LA[(r0+1)*1032 + d] = f2b(v.y);
    LA[(r0+2)*1032 + d] = f2b(v.z);
    LA[(r0+3)*1032 + d] = f2b(v.w);
  }
  __syncthreads();
  int start = starts[s], cnt = starts[s+1] - start;
  if (cnt == 0) return;
  int lane = t & 63, wave = t >> 6;
  int l15 = lane & 15, kq = (lane >> 4) * 8;
  int ntiles = (cnt + 15) >> 4;
  for (int mt = wave*2; mt < ntiles; mt += 8){
    bool two = (mt + 1 < ntiles);
    int m0 = mt*16 + l15;       if (m0 >= cnt) m0 = cnt - 1;
    int m1 = (mt+1)*16 + l15;   if (m1 >= cnt) m1 = cnt - 1;
    int e0 = order[start + m0];
    int e1 = two ? order[start + m1] : e0;
    const unsigned short* A0 = XC + (size_t)e0*2048 + kofs + kq;
    const unsigned short* A1 = XC + (size_t)e1*2048 + kofs + kq;
    const unsigned short* Bp = &LA[l15*1032 + kq];
    f32x4 acc0 = {}, acc1 = {};
    #pragma unroll 4
    for (int kt = 0; kt < 1024; kt += 32){
      s16x8 a0 = *(const s16x8*)(A0 + kt);
      s16x8 a1 = *(const s16x8*)(A1 + kt);
      s16x8 b  = *(const s16x8*)(Bp + kt);
      acc0 = __builtin_amdgcn_mfma_f32_16x16x32_bf16(a0, b, acc0, 0, 0, 0);
      acc1 = __builtin_amdgcn_mfma_f32_16x16x32_bf16(a1, b, acc1, 0, 0, 0);
    }
    int rowb = (lane >> 4) * 4;
    #pragma unroll
    for (int i = 0; i < 4; i++){
      int m = mt*16 + rowb + i;
      if (m < cnt){
        int e = order[start + m];
        low[((size_t)g*B_ + e)*R_ + l15] = acc0[i];
      }
    }
    if (two){
      #pragma unroll
      for (int i = 0; i < 4; i++){
        int m = (mt+1)*16 + rowb + i;
        if (m < cnt){
          int e = order[start + m];
          low[((size_t)g*B_ + e)*R_ + l15] = acc1[i];
        }
      }
    }
  }
}

// ---------------- kernel 4: MFMA GEMM (6 uniform units, 2-phase dbuf prefetch) ------------
__global__ __launch_bounds__(256, 3) void gemm_kernel(
    const unsigned short* __restrict__ XC,
    const unsigned short* __restrict__ Wt_all,
    float* __restrict__ Yall){
  int u = blockIdx.y;
  const unsigned short* Wt = Wt_all + (size_t)u * (1024*1024);
  float* Y = Yall + (size_t)u * ((size_t)B_ * F_);
  int kofs = (u & 1) << 10;

  __shared__ unsigned short As[2][128*32];
  __shared__ unsigned short Bs[2][128*32];

  int t = threadIdx.x;
  int lane = t & 63, wave = t >> 6;
  int mt = blockIdx.x >> 3, nt = blockIdx.x & 7;
  int row0 = mt * 128, col0 = nt * 128;
  int wrow = (wave >> 1) * 64, wcol = (wave & 1) * 64;

  int arow = t >> 2;
  int achk = (t & 3) * 8;

  const unsigned short* Ab  = XC + (size_t)(row0 + arow) * 2048 + kofs + achk;
  const unsigned short* Ab2 = Ab + (size_t)64 * 2048;
  const unsigned short* Bb  = Wt + (size_t)(col0 + arow) * 1024 + achk;
  const unsigned short* Bb2 = Bb + (size_t)64 * 1024;

  int l15 = lane & 15, kof = (lane >> 4) * 8;
  f32x4 acc[4][4] = {};

  gload16(Ab,  &As[0][t*8]);  gload16(Ab2, &As[0][2048 + t*8]);
  gload16(Bb,  &Bs[0][t*8]);  gload16(Bb2, &Bs[0][2048 + t*8]);
  __syncthreads();

  int cur = 0;
  for (int kt = 32; kt < 1024; kt += 32){
    int nxt = cur ^ 1;
    gload16(Ab  + kt, &As[nxt][t*8]);  gload16(Ab2 + kt, &As[nxt][2048 + t*8]);
    gload16(Bb  + kt, &Bs[nxt][t*8]);  gload16(Bb2 + kt, &Bs[nxt][2048 + t*8]);
    s16x8 af[4], bfr[4];
    #pragma unroll
    for (int m = 0; m < 4; m++)
      af[m] = *(const s16x8*)&As[cur][(wrow + m*16 + l15)*32 + kof];
    #pragma unroll
    for (int n = 0; n < 4; n++)
      bfr[n] = *(const s16x8*)&Bs[cur][(wcol + n*16 + l15)*32 + kof];
    #pragma unroll
    for (int m = 0; m < 4; m++){
      #pragma unroll
      for (int n = 0; n < 4; n++){
        acc[m][n] = __builtin_amdgcn_mfma_f32_16x16x32_bf16(af[m], bfr[n], acc[m][n], 0, 0, 0);
      }
    }
    __syncthreads();
    cur = nxt;
  }
  {
    s16x8 af[4], bfr[4];
    #pragma unroll
    for (int m = 0; m < 4; m++)
      af[m] = *(const s16x8*)&As[cur][(wrow + m*16 + l15)*32 + kof];
    #pragma unroll
    for (int n = 0; n < 4; n++)
      bfr[n] = *(const s16x8*)&Bs[cur][(wcol + n*16 + l15)*32 + kof];
    #pragma unroll
    for (int m = 0; m < 4; m++){
      #pragma unroll
      for (int n = 0; n < 4; n++){
        acc[m][n] = __builtin_amdgcn_mfma_f32_16x16x32_bf16(af[m], bfr[n], acc[m][n], 0, 0, 0);
      }
    }
  }

  int orow = row0 + wrow + (lane >> 4) * 4;
  int ocol = col0 + wcol + l15;
  #pragma unroll
  for (int m = 0; m < 4; m++){
    #pragma unroll
    for (int n = 0; n < 4; n++){
      #pragma unroll
      for (int i = 0; i < 4; i++){
        Y[(size_t)(orow + m*16 + i) * F_ + ocol + n*16] = acc[m][n][i];
      }
    }
  }
}

// ---------------- kernel 5: MFMA delta, RMW into Y0/Y2/Y4/Y5 (bucketed) ----------------
// dr = [low_ir|low_rr] @ [lb_ir;lb_rr]  -> += Y0
// du = [low_iu|low_ru] @ [lb_iu;lb_ru]  -> += Y2
// dic= [low_ic|  0  ] @ [lb_ic;lb_rc]   -> += Y4
// drc= [  0  |low_rc] @ [lb_ic;lb_rc]   -> += Y5
__global__ __launch_bounds__(256) void delta_kernel(
    const float* __restrict__ lb_ir, const float* __restrict__ lb_rr,
    const float* __restrict__ lb_iu, const float* __restrict__ lb_ru,
    const float* __restrict__ lb_ic, const float* __restrict__ lb_rc,
    const int* __restrict__ starts, const int* __restrict__ order,
    const float* __restrict__ low, float* __restrict__ Yall){
  int s = blockIdx.x;
  int c0 = blockIdx.y * 128;
  // 3 B-matrices [col 0..127][k 0..31], element stride 40 (80B rows: 16B-aligned, ~2-way banks)
  __shared__ unsigned short Bs[3 * 128 * 40];
  int t = threadIdx.x;
  const float* lbp[6] = {lb_ir, lb_rr, lb_iu, lb_ru, lb_ic, lb_rc};
  #pragma unroll
  for (int j = 0; j < 6; j++){
    const float* lb = lbp[j] + (size_t)s * R_ * F_;
    unsigned short* Bj = &Bs[(j >> 1)*5120 + (j & 1)*16];
    #pragma unroll
    for (int it = 0; it < 2; it++){
      int idx = t + it*256;                 // 512 float4 per lb
      int r = idx >> 5, c4 = (idx & 31) * 4;
      float4 v = *(const float4*)&lb[(size_t)r*F_ + c0 + c4];
      Bj[(c4+0)*40 + r] = f2b(v.x);
      Bj[(c4+1)*40 + r] = f2b(v.y);
      Bj[(c4+2)*40 + r] = f2b(v.z);
      Bj[(c4+3)*40 + r] = f2b(v.w);
    }
  }
  __syncthreads();
  int start = starts[s], cnt = starts[s+1] - start;
  if (cnt == 0) return;
  int lane = t & 63, wave = t >> 6;
  int l15 = lane & 15, kq = (lane >> 4) * 8;   // 0,8,16,24
  int ntiles = (cnt + 15) >> 4;
  float* Y0 = Yall + 0*(size_t)B_*F_;
  float* Y2 = Yall + 2*(size_t)B_*F_;
  float* Y4 = Yall + 4*(size_t)B_*F_;
  float* Y5 = Yall + 5*(size_t)B_*F_;
  int k8 = kq & 15; bool hi = (kq >= 16);
  for (int mt = wave; mt < ntiles; mt += 4){
    int m = mt*16 + l15; if (m >= cnt) m = cnt - 1;
    int e = order[start + m];
    s16x8 a_r, a_u, a_c1 = {}, a_c2 = {};
    {
      const float* p = &low[((size_t)(hi ? 3 : 0)*B_ + e)*R_ + k8];
      float4 v0 = *(const float4*)p, v1 = *(const float4*)(p+4);
      a_r[0]=f2b(v0.x); a_r[1]=f2b(v0.y); a_r[2]=f2b(v0.z); a_r[3]=f2b(v0.w);
      a_r[4]=f2b(v1.x); a_r[5]=f2b(v1.y); a_r[6]=f2b(v1.z); a_r[7]=f2b(v1.w);
    }
    {
      const float* p = &low[((size_t)(hi ? 4 : 1)*B_ + e)*R_ + k8];
      float4 v0 = *(const float4*)p, v1 = *(const float4*)(p+4);
      a_u[0]=f2b(v0.x); a_u[1]=f2b(v0.y); a_u[2]=f2b(v0.z); a_u[3]=f2b(v0.w);
      a_u[4]=f2b(v1.x); a_u[5]=f2b(v1.y); a_u[6]=f2b(v1.z); a_u[7]=f2b(v1.w);
    }
    if (!hi){
      const float* p = &low[((size_t)2*B_ + e)*R_ + k8];
      float4 v0 = *(const float4*)p, v1 = *(const float4*)(p+4);
      a_c1[0]=f2b(v0.x); a_c1[1]=f2b(v0.y); a_c1[2]=f2b(v0.z); a_c1[3]=f2b(v0.w);
      a_c1[4]=f2b(v1.x); a_c1[5]=f2b(v1.y); a_c1[6]=f2b(v1.z); a_c1[7]=f2b(v1.w);
    } else {
      const float* p = &low[((size_t)5*B_ + e)*R_ + k8];
      float4 v0 = *(const float4*)p, v1 = *(const float4*)(p+4);
      a_c2[0]=f2b(v0.x); a_c2[1]=f2b(v0.y); a_c2[2]=f2b(v0.z); a_c2[3]=f2b(v0.w);
      a_c2[4]=f2b(v1.x); a_c2[5]=f2b(v1.y); a_c2[6]=f2b(v1.z); a_c2[7]=f2b(v1.w);
    }
    int rowb = (lane >> 4) * 4;
    int erow[4]; bool wok[4];
    #pragma unroll
    for (int i = 0; i < 4; i++){
      int mm = mt*16 + rowb + i;
      wok[i] = (mm < cnt);
      erow[i] = order[start + (wok[i] ? mm : cnt - 1)];
    }
    #pragma unroll
    for (int cf = 0; cf < 8; cf++){
      int col = cf*16 + l15;
      s16x8 b_r = *(const s16x8*)&Bs[0*5120 + col*40 + kq];
      s16x8 b_u = *(const s16x8*)&Bs[1*5120 + col*40 + kq];
      s16x8 b_c = *(const s16x8*)&Bs[2*5120 + col*40 + kq];
      f32x4 zero = {};
      f32x4 dr  = __builtin_amdgcn_mfma_f32_16x16x32_bf16(a_r,  b_r, zero, 0, 0, 0);
      f32x4 du  = __builtin_amdgcn_mfma_f32_16x16x32_bf16(a_u,  b_u, zero, 0, 0, 0);
      f32x4 dic = __builtin_amdgcn_mfma_f32_16x16x32_bf16(a_c1, b_c, zero, 0, 0, 0);
      f32x4 drc = __builtin_amdgcn_mfma_f32_16x16x32_bf16(a_c2, b_c, zero, 0, 0, 0);
      int oc = c0 + cf*16 + l15;
      #pragma unroll
      for (int i = 0; i < 4; i++){
        if (wok[i]){
          size_t idx = (size_t)erow[i]*F_ + oc;
          Y0[idx] += dr[i];
          Y2[idx] += du[i];
          Y4[idx] += dic[i];
          Y5[idx] += drc[i];
        }
      }
    }
  }
}

// ---------------- kernel 6: streaming gates + output ----------------
__global__ void final_kernel(const float* __restrict__ carry,
                             const float* __restrict__ bias_ir, const float* __restrict__ bias_iu,
                             const float* __restrict__ bias_ic,
                             const float* __restrict__ Yall,
                             float* __restrict__ out){
  int i = blockIdx.x * blockDim.x + threadIdx.x;
  if (i >= B_ * F_ / 4) return;
  int j = (i & 255) * 4;
  size_t idx = (size_t)i * 4;
  const float* Y0 = Yall + 0*(size_t)B_*F_;
  const float* Y1 = Yall + 1*(size_t)B_*F_;
  const float* Y2 = Yall + 2*(size_t)B_*F_;
  const float* Y3 = Yall + 3*(size_t)B_*F_;
  const float* Y4 = Yall + 4*(size_t)B_*F_;
  const float* Y5 = Yall + 5*(size_t)B_*F_;
  float4 y0 = *(const float4*)&Y0[idx];
  float4 y1 = *(const float4*)&Y1[idx];
  float4 y2 = *(const float4*)&Y2[idx];
  float4 y3 = *(const float4*)&Y3[idx];
  float4 y4 = *(const float4*)&Y4[idx];
  float4 y5 = *(const float4*)&Y5[idx];
  float4 br = *(const float4*)&bias_ir[j];
  float4 bu = *(const float4*)&bias_iu[j];
  float4 bc = *(const float4*)&bias_ic[j];
  float4 cv = *(const float4*)&carry[idx];
  float4 o;
  float zr, zu, zic, zrc, rr, uu, cand, e;
  zr = y0.x + y1.x + br.x;  rr = 1.f/(1.f+__expf(-zr));
  zu = y2.x + y3.x + bu.x;  uu = 1.f/(1.f+__expf(-zu));
  zic = y4.x + bc.x;  zrc = y5.x;
  { float a = zic + rr*zrc; e = __expf(-2.f*fabsf(a)); cand = copysignf((1.f-e)/(1.f+e), a); }
  o.x = (1.f-uu)*cand + uu*cv.x;
  zr = y0.y + y1.y + br.y;  rr = 1.f/(1.f+__expf(-zr));
  zu = y2.y + y3.y + bu.y;  uu = 1.f/(1.f+__expf(-zu));
  zic = y4.y + bc.y;  zrc = y5.y;
  { float a = zic + rr*zrc; e = __expf(-2.f*fabsf(a)); cand = copysignf((1.f-e)/(1.f+e), a); }
  o.y = (1.f-uu)*cand + uu*cv.y;
  zr = y0.z + y1.z + br.z;  rr = 1.f/(1.f+__expf(-zr));
  zu = y2.z + y3.z + bu.z;  uu = 1.f/(1.f+__expf(-zu));
  zic = y4.z + bc.z;  zrc = y5.z;
  { float a = zic + rr*zrc; e = __expf(-2.f*fabsf(a)); cand = copysignf((1.f-e)/(1.f+e), a); }
  o.z = (1.f-uu)*cand + uu*cv.z;
  zr = y0.w + y1.w + br.w;  rr = 1.f/(1.f+__expf(-zr));
  zu = y2.w + y3.w + bu.w;  uu = 1.f/(1.f+__expf(-zu));
  zic = y4.w + bc.w;  zrc = y5.w;
  { float a = zic + rr*zrc; e = __expf(-2.f*fabsf(a)); cand = copysignf((1.f-e)/(1.f+e), a); }
  o.w = (1.f-uu)*cand + uu*cv.w;
  *(float4*)&out[idx] = o;
}

extern "C" void kernel_launch(void* const* d_in, const int* in_sizes, int n_in,
                              void* d_out, int out_size, void* d_ws, size_t ws_size,
                              hipStream_t stream){
  const float* carry   = (const float*)d_in[0];
  const float* x       = (const float*)d_in[1];
  const int*   ids     = (const int*)d_in[2];
  const float* w_ir    = (const float*)d_in[3];
  const float* bias_ir = (const float*)d_in[4];
  const float* la_ir   = (const float*)d_in[5];
  const float* lb_ir   = (const float*)d_in[6];
  const float* w_iu    = (const float*)d_in[7];
  const float* bias_iu = (const float*)d_in[8];
  const float* la_iu   = (const float*)d_in[9];
  const float* lb_iu   = (const float*)d_in[10];
  const float* w_ic    = (const float*)d_in[11];
  const float* bias_ic = (const float*)d_in[12];
  const float* la_ic   = (const float*)d_in[13];
  const float* lb_ic   = (const float*)d_in[14];
  const float* w_rr    = (const float*)d_in[15];
  const float* la_rr   = (const float*)d_in[16];
  const float* lb_rr   = (const float*)d_in[17];
  const float* w_ru    = (const float*)d_in[18];
  const float* la_ru   = (const float*)d_in[19];
  const float* lb_ru   = (const float*)d_in[20];
  const float* w_rc    = (const float*)d_in[21];
  const float* la_rc   = (const float*)d_in[22];
  const float* lb_rc   = (const float*)d_in[23];

  char* ws = (char*)d_ws;
  unsigned short* XC     = (unsigned short*)(ws + 0);          // 8 MiB
  unsigned short* Wt_all = (unsigned short*)(ws + 8388608);    // 12 MiB (6 x 2 MiB)
  float* Yall = (float*)(ws + 20971520);                       // 48 MiB (6 x 8 MiB)
  float* low  = (float*)(ws + 71303168);                       // 768 KiB
  int* starts = (int*)(ws + 72089600);
  int* order  = (int*)(ws + 72090624);

  cast_xc_kernel<<<dim3(2048), dim3(256), 0, stream>>>(x, carry, XC);
  wcast_kernel<<<dim3(256, 6), dim3(256), 0, stream>>>(w_ir, w_rr, w_iu, w_ru, w_ic, w_rc,
                                                       Wt_all);
  bucket_kernel<<<dim3(1), dim3(256), 0, stream>>>(ids, starts, order);
  low_kernel<<<dim3(64, 6), dim3(256), 0, stream>>>(XC, la_ir, la_iu, la_ic,
                                                    la_rr, la_ru, la_rc, starts, order, low);
  gemm_kernel<<<dim3(128, 6), dim3(256), 0, stream>>>(XC, Wt_all, Yall);
  delta_kernel<<<dim3(64, 8), dim3(256), 0, stream>>>(lb_ir, lb_rr, lb_iu, lb_ru, lb_ic, lb_rc,
                                                      starts, order, low, Yall);
  final_kernel<<<dim3(2048), dim3(256), 0, stream>>>(carry, bias_ir, bias_iu, bias_ic,
                                                     Yall, (float*)d_out);
}

// Round 5
// 102.709 us; speedup vs baseline: 1.2650x; 1.0860x over previous
//
#include <hip/hip_runtime.h>
#include <stdint.h>

#define B_  2048
#define D_  1024
#define F_  1024
#define S_  64
#define R_  16

typedef __attribute__((ext_vector_type(8))) short  s16x8;
typedef __attribute__((ext_vector_type(4))) unsigned short u16x4;
typedef __attribute__((ext_vector_type(8))) unsigned short u16x8;
typedef __attribute__((ext_vector_type(4))) float  f32x4;

__device__ __forceinline__ unsigned short f2b(float f){
  unsigned u = __float_as_uint(f);
  u = u + 0x7fffu + ((u >> 16) & 1u);   // RNE to bf16
  return (unsigned short)(u >> 16);
}
__device__ __forceinline__ float b2f(unsigned short s){
  return __uint_as_float(((unsigned)s) << 16);
}

__device__ __forceinline__ void gload16(const void* g, void* l){
  __builtin_amdgcn_global_load_lds((const __attribute__((address_space(1))) unsigned int*)g,
                                   (__attribute__((address_space(3))) unsigned int*)l, 16, 0, 0);
}

// ---------------- kernel 1a: XC = [bf16(x) | bf16(carry)]  (B x 2048) ----------------
__global__ void cast_xc_kernel(const float* __restrict__ x, const float* __restrict__ carry,
                               unsigned short* __restrict__ XC){
  int i = blockIdx.x * blockDim.x + threadIdx.x;
  if (i >= B_ * (D_/4)) return;
  int b = i >> 8;
  int j = (i & 255) * 4;
  float4 xv = *(const float4*)&x[(size_t)b*D_ + j];
  float4 cv = *(const float4*)&carry[(size_t)b*F_ + j];
  u16x4 xs, cs;
  xs[0]=f2b(xv.x); xs[1]=f2b(xv.y); xs[2]=f2b(xv.z); xs[3]=f2b(xv.w);
  cs[0]=f2b(cv.x); cs[1]=f2b(cv.y); cs[2]=f2b(cv.z); cs[3]=f2b(cv.w);
  *(u16x4*)&XC[(size_t)b*2048 + j]        = xs;
  *(u16x4*)&XC[(size_t)b*2048 + 1024 + j] = cs;
}

// ---------------- kernel 1b: transpose-cast 6 weights into Wt_all[u][n][k] bf16 -----------
// unit order: 0=ir(x), 1=rr(c), 2=iu(x), 3=ru(c), 4=ic(x), 5=rc(c)
__global__ void wcast_kernel(const float* __restrict__ w_ir, const float* __restrict__ w_rr,
                             const float* __restrict__ w_iu, const float* __restrict__ w_ru,
                             const float* __restrict__ w_ic, const float* __restrict__ w_rc,
                             unsigned short* __restrict__ Wt_all){
  int u = blockIdx.y;
  const float* W;
  switch(u){ case 0: W=w_ir; break; case 1: W=w_rr; break; case 2: W=w_iu; break;
             case 3: W=w_ru; break; case 4: W=w_ic; break; default: W=w_rc; break; }
  unsigned short* O = Wt_all + (size_t)u * (1024*1024);
  __shared__ unsigned short T[64][72];   // row stride 144B (9*16B)
  int t = threadIdx.x;
  int n0 = (blockIdx.x & 15) * 64;
  int k0 = (blockIdx.x >> 4) * 64;
  int c4 = (t & 15) * 4;
  int kk = t >> 4;
  #pragma unroll
  for (int i = 0; i < 4; i++){
    int k = kk + i*16;
    float4 v = *(const float4*)&W[(size_t)(k0+k)*F_ + n0 + c4];
    T[c4+0][k] = f2b(v.x); T[c4+1][k] = f2b(v.y); T[c4+2][k] = f2b(v.z); T[c4+3][k] = f2b(v.w);
  }
  __syncthreads();
  int n = t >> 2, ch = (t & 3) * 16;
  u16x8 a = *(const u16x8*)&T[n][ch];
  u16x8 b = *(const u16x8*)&T[n][ch+8];
  *(u16x8*)&O[(size_t)(n0+n)*1024 + k0 + ch]     = a;
  *(u16x8*)&O[(size_t)(n0+n)*1024 + k0 + ch + 8] = b;
}

// ---------------- kernel 2: bucket examples by adapter id ----------------
__global__ void bucket_kernel(const int* __restrict__ ids, int* __restrict__ starts,
                              int* __restrict__ order){
  __shared__ int cnt[S_]; __shared__ int off[S_+1]; __shared__ int cur[S_];
  int t = threadIdx.x;
  if (t < S_) cnt[t] = 0;
  __syncthreads();
  for (int b = t; b < B_; b += 256) atomicAdd(&cnt[ids[b]], 1);
  __syncthreads();
  if (t == 0){ off[0] = 0; for (int s2 = 0; s2 < S_; s2++) off[s2+1] = off[s2] + cnt[s2]; }
  __syncthreads();
  if (t < S_) cur[t] = off[t];
  __syncthreads();
  for (int b = t; b < B_; b += 256){ int p = atomicAdd(&cur[ids[b]], 1); order[p] = b; }
  if (t < S_+1) starts[t] = off[t];
}

// ---------------- kernel 3: low[g][b][r] = XC[b, gslice] . la_g[id[b]][:,r]  (MFMA) ------
// g order: 0=ir, 1=iu, 2=ic, 3=rr, 4=ru, 5=rc
__global__ __launch_bounds__(256) void low_kernel(
    const unsigned short* __restrict__ XC,
    const float* __restrict__ la_ir, const float* __restrict__ la_iu,
    const float* __restrict__ la_ic, const float* __restrict__ la_rr,
    const float* __restrict__ la_ru, const float* __restrict__ la_rc,
    const int* __restrict__ starts, const int* __restrict__ order,
    float* __restrict__ low){
  int s = blockIdx.x, g = blockIdx.y;
  const float* la;
  switch(g){ case 0: la=la_ir; break; case 1: la=la_iu; break; case 2: la=la_ic; break;
             case 3: la=la_rr; break; case 4: la=la_ru; break; default: la=la_rc; break; }
  int kofs = (g < 3) ? 0 : 1024;
  la += (size_t)s * D_ * R_;
  __shared__ unsigned short LA[16 * 1032];   // [r][d], pad 8
  int t = threadIdx.x;
  for (int i4 = t; i4 < D_*R_/4; i4 += 256){
    float4 v = *(const float4*)&la[i4*4];
    int d = i4 >> 2, r0 = (i4 & 3) * 4;
    LA[(r0+0)*1032 + d] = f2b(v.x);
    LA[(r0+1)*1032 + d] = f2b(v.y);
    LA[(r0+2)*1032 + d] = f2b(v.z);
    LA[(r0+3)*1032 + d] = f2b(v.w);
  }
  __syncthreads();
  int start = starts[s], cnt = starts[s+1] - start;
  if (cnt == 0) return;
  int lane = t & 63, wave = t >> 6;
  int l15 = lane & 15, kq = (lane >> 4) * 8;
  int ntiles = (cnt + 15) >> 4;
  for (int mt = wave*2; mt < ntiles; mt += 8){
    bool two = (mt + 1 < ntiles);
    int m0 = mt*16 + l15;       if (m0 >= cnt) m0 = cnt - 1;
    int m1 = (mt+1)*16 + l15;   if (m1 >= cnt) m1 = cnt - 1;
    int e0 = order[start + m0];
    int e1 = two ? order[start + m1] : e0;
    const unsigned short* A0 = XC + (size_t)e0*2048 + kofs + kq;
    const unsigned short* A1 = XC + (size_t)e1*2048 + kofs + kq;
    const unsigned short* Bp = &LA[l15*1032 + kq];
    f32x4 acc0 = {}, acc1 = {};
    #pragma unroll 4
    for (int kt = 0; kt < 1024; kt += 32){
      s16x8 a0 = *(const s16x8*)(A0 + kt);
      s16x8 a1 = *(const s16x8*)(A1 + kt);
      s16x8 b  = *(const s16x8*)(Bp + kt);
      acc0 = __builtin_amdgcn_mfma_f32_16x16x32_bf16(a0, b, acc0, 0, 0, 0);
      acc1 = __builtin_amdgcn_mfma_f32_16x16x32_bf16(a1, b, acc1, 0, 0, 0);
    }
    int rowb = (lane >> 4) * 4;
    #pragma unroll
    for (int i = 0; i < 4; i++){
      int m = mt*16 + rowb + i;
      if (m < cnt){
        int e = order[start + m];
        low[((size_t)g*B_ + e)*R_ + l15] = acc0[i];
      }
    }
    if (two){
      #pragma unroll
      for (int i = 0; i < 4; i++){
        int m = (mt+1)*16 + rowb + i;
        if (m < cnt){
          int e = order[start + m];
          low[((size_t)g*B_ + e)*R_ + l15] = acc1[i];
        }
      }
    }
  }
}

// ---------------- kernel 4: MFMA GEMM (6 uniform units, 2-phase dbuf, swizzled LDS) -------
// LDS k-slot swizzle: physical slot p of row r holds logical k-slot p ^ ((r>>1)&3).
// Staged by permuting per-lane global source; read compensates. Kills the 8-way
// ds_read_b128 bank conflict (bank-group = 4*(l15&1) + q^((l15>>1)&3): 8 distinct).
__global__ __launch_bounds__(256, 3) void gemm_kernel(
    const unsigned short* __restrict__ XC,
    const unsigned short* __restrict__ Wt_all,
    float* __restrict__ Yall){
  int u = blockIdx.y;
  const unsigned short* Wt = Wt_all + (size_t)u * (1024*1024);
  float* Y = Yall + (size_t)u * ((size_t)B_ * F_);
  int kofs = (u & 1) << 10;

  __shared__ unsigned short As[2][128*32];
  __shared__ unsigned short Bs[2][128*32];

  int t = threadIdx.x;
  int lane = t & 63, wave = t >> 6;
  int mt = blockIdx.x >> 3, nt = blockIdx.x & 7;
  int row0 = mt * 128, col0 = nt * 128;
  int wrow = (wave >> 1) * 64, wcol = (wave & 1) * 64;

  int arow = t >> 2;
  int achk = ((t & 3) ^ ((t >> 3) & 3)) * 8;   // swizzled source k-slot

  const unsigned short* Ab  = XC + (size_t)(row0 + arow) * 2048 + kofs + achk;
  const unsigned short* Ab2 = Ab + (size_t)64 * 2048;
  const unsigned short* Bb  = Wt + (size_t)(col0 + arow) * 1024 + achk;
  const unsigned short* Bb2 = Bb + (size_t)64 * 1024;

  int l15 = lane & 15;
  int kof = (((lane >> 4) ^ ((l15 >> 1) & 3)) * 8);   // swizzled read slot
  f32x4 acc[4][4] = {};

  gload16(Ab,  &As[0][t*8]);  gload16(Ab2, &As[0][2048 + t*8]);
  gload16(Bb,  &Bs[0][t*8]);  gload16(Bb2, &Bs[0][2048 + t*8]);
  __syncthreads();

  int cur = 0;
  for (int kt = 32; kt < 1024; kt += 32){
    int nxt = cur ^ 1;
    gload16(Ab  + kt, &As[nxt][t*8]);  gload16(Ab2 + kt, &As[nxt][2048 + t*8]);
    gload16(Bb  + kt, &Bs[nxt][t*8]);  gload16(Bb2 + kt, &Bs[nxt][2048 + t*8]);
    s16x8 af[4], bfr[4];
    #pragma unroll
    for (int m = 0; m < 4; m++)
      af[m] = *(const s16x8*)&As[cur][(wrow + m*16 + l15)*32 + kof];
    #pragma unroll
    for (int n = 0; n < 4; n++)
      bfr[n] = *(const s16x8*)&Bs[cur][(wcol + n*16 + l15)*32 + kof];
    #pragma unroll
    for (int m = 0; m < 4; m++){
      #pragma unroll
      for (int n = 0; n < 4; n++){
        acc[m][n] = __builtin_amdgcn_mfma_f32_16x16x32_bf16(af[m], bfr[n], acc[m][n], 0, 0, 0);
      }
    }
    __syncthreads();
    cur = nxt;
  }
  {
    s16x8 af[4], bfr[4];
    #pragma unroll
    for (int m = 0; m < 4; m++)
      af[m] = *(const s16x8*)&As[cur][(wrow + m*16 + l15)*32 + kof];
    #pragma unroll
    for (int n = 0; n < 4; n++)
      bfr[n] = *(const s16x8*)&Bs[cur][(wcol + n*16 + l15)*32 + kof];
    #pragma unroll
    for (int m = 0; m < 4; m++){
      #pragma unroll
      for (int n = 0; n < 4; n++){
        acc[m][n] = __builtin_amdgcn_mfma_f32_16x16x32_bf16(af[m], bfr[n], acc[m][n], 0, 0, 0);
      }
    }
  }

  int orow = row0 + wrow + (lane >> 4) * 4;
  int ocol = col0 + wcol + l15;
  #pragma unroll
  for (int m = 0; m < 4; m++){
    #pragma unroll
    for (int n = 0; n < 4; n++){
      #pragma unroll
      for (int i = 0; i < 4; i++){
        Y[(size_t)(orow + m*16 + i) * F_ + ocol + n*16] = acc[m][n][i];
      }
    }
  }
}

// ---------------- kernel 5: fused MFMA delta + GRU gates + output (bucketed) ----------------
// dr = [low_ir|low_rr] @ [lb_ir;lb_rr] ; du = [low_iu|low_ru] @ [lb_iu;lb_ru]
// dic= [low_ic|0] @ [lb_ic;lb_rc]     ; drc= [0|low_rc] @ [lb_ic;lb_rc]
// then gates: r=sig(Y0+Y1+b_ir+dr), u=sig(Y2+Y3+b_iu+du),
//             cand=tanh(Y4+b_ic+dic + r*(Y5+drc)), out=(1-u)cand+u*carry
__global__ __launch_bounds__(256) void delta_final_kernel(
    const float* __restrict__ carry,
    const float* __restrict__ bias_ir, const float* __restrict__ bias_iu,
    const float* __restrict__ bias_ic,
    const float* __restrict__ lb_ir, const float* __restrict__ lb_rr,
    const float* __restrict__ lb_iu, const float* __restrict__ lb_ru,
    const float* __restrict__ lb_ic, const float* __restrict__ lb_rc,
    const int* __restrict__ starts, const int* __restrict__ order,
    const float* __restrict__ low, const float* __restrict__ Yall,
    float* __restrict__ out){
  int s = blockIdx.x;
  int c0 = blockIdx.y * 128;
  __shared__ unsigned short Bs[3 * 128 * 40];   // 3 stacked [col][k0..31], stride 40
  int t = threadIdx.x;
  const float* lbp[6] = {lb_ir, lb_rr, lb_iu, lb_ru, lb_ic, lb_rc};
  #pragma unroll
  for (int j = 0; j < 6; j++){
    const float* lb = lbp[j] + (size_t)s * R_ * F_;
    unsigned short* Bj = &Bs[(j >> 1)*5120 + (j & 1)*16];
    #pragma unroll
    for (int it = 0; it < 2; it++){
      int idx = t + it*256;
      int r = idx >> 5, c4 = (idx & 31) * 4;
      float4 v = *(const float4*)&lb[(size_t)r*F_ + c0 + c4];
      Bj[(c4+0)*40 + r] = f2b(v.x);
      Bj[(c4+1)*40 + r] = f2b(v.y);
      Bj[(c4+2)*40 + r] = f2b(v.z);
      Bj[(c4+3)*40 + r] = f2b(v.w);
    }
  }
  __syncthreads();
  int start = starts[s], cnt = starts[s+1] - start;
  if (cnt == 0) return;
  int lane = t & 63, wave = t >> 6;
  int l15 = lane & 15, kq = (lane >> 4) * 8;   // 0,8,16,24
  int ntiles = (cnt + 15) >> 4;
  const float* Y0 = Yall + 0*(size_t)B_*F_;
  const float* Y1 = Yall + 1*(size_t)B_*F_;
  const float* Y2 = Yall + 2*(size_t)B_*F_;
  const float* Y3 = Yall + 3*(size_t)B_*F_;
  const float* Y4 = Yall + 4*(size_t)B_*F_;
  const float* Y5 = Yall + 5*(size_t)B_*F_;
  int k8 = kq & 15; bool hi = (kq >= 16);
  // work items: (m-tile, cf-half) pairs for wave balance at small cnt
  for (int pt = wave; pt < ntiles*2; pt += 4){
    int mt = pt >> 1, cf0 = (pt & 1) * 4;
    int m = mt*16 + l15; if (m >= cnt) m = cnt - 1;
    int e = order[start + m];
    s16x8 a_r, a_u, a_c1 = {}, a_c2 = {};
    {
      const float* p = &low[((size_t)(hi ? 3 : 0)*B_ + e)*R_ + k8];
      float4 v0 = *(const float4*)p, v1 = *(const float4*)(p+4);
      a_r[0]=f2b(v0.x); a_r[1]=f2b(v0.y); a_r[2]=f2b(v0.z); a_r[3]=f2b(v0.w);
      a_r[4]=f2b(v1.x); a_r[5]=f2b(v1.y); a_r[6]=f2b(v1.z); a_r[7]=f2b(v1.w);
    }
    {
      const float* p = &low[((size_t)(hi ? 4 : 1)*B_ + e)*R_ + k8];
      float4 v0 = *(const float4*)p, v1 = *(const float4*)(p+4);
      a_u[0]=f2b(v0.x); a_u[1]=f2b(v0.y); a_u[2]=f2b(v0.z); a_u[3]=f2b(v0.w);
      a_u[4]=f2b(v1.x); a_u[5]=f2b(v1.y); a_u[6]=f2b(v1.z); a_u[7]=f2b(v1.w);
    }
    if (!hi){
      const float* p = &low[((size_t)2*B_ + e)*R_ + k8];
      float4 v0 = *(const float4*)p, v1 = *(const float4*)(p+4);
      a_c1[0]=f2b(v0.x); a_c1[1]=f2b(v0.y); a_c1[2]=f2b(v0.z); a_c1[3]=f2b(v0.w);
      a_c1[4]=f2b(v1.x); a_c1[5]=f2b(v1.y); a_c1[6]=f2b(v1.z); a_c1[7]=f2b(v1.w);
    } else {
      const float* p = &low[((size_t)5*B_ + e)*R_ + k8];
      float4 v0 = *(const float4*)p, v1 = *(const float4*)(p+4);
      a_c2[0]=f2b(v0.x); a_c2[1]=f2b(v0.y); a_c2[2]=f2b(v0.z); a_c2[3]=f2b(v0.w);
      a_c2[4]=f2b(v1.x); a_c2[5]=f2b(v1.y); a_c2[6]=f2b(v1.z); a_c2[7]=f2b(v1.w);
    }
    int rowb = (lane >> 4) * 4;
    int erow[4]; bool wok[4];
    #pragma unroll
    for (int i = 0; i < 4; i++){
      int mm = mt*16 + rowb + i;
      wok[i] = (mm < cnt);
      erow[i] = order[start + (wok[i] ? mm : cnt - 1)];
    }
    #pragma unroll
    for (int cf = cf0; cf < cf0 + 4; cf++){
      int col = cf*16 + l15;
      s16x8 b_r = *(const s16x8*)&Bs[0*5120 + col*40 + kq];
      s16x8 b_u = *(const s16x8*)&Bs[1*5120 + col*40 + kq];
      s16x8 b_c = *(const s16x8*)&Bs[2*5120 + col*40 + kq];
      f32x4 zero = {};
      f32x4 dr  = __builtin_amdgcn_mfma_f32_16x16x32_bf16(a_r,  b_r, zero, 0, 0, 0);
      f32x4 du  = __builtin_amdgcn_mfma_f32_16x16x32_bf16(a_u,  b_u, zero, 0, 0, 0);
      f32x4 dic = __builtin_amdgcn_mfma_f32_16x16x32_bf16(a_c1, b_c, zero, 0, 0, 0);
      f32x4 drc = __builtin_amdgcn_mfma_f32_16x16x32_bf16(a_c2, b_c, zero, 0, 0, 0);
      int oc = c0 + col;
      float br = bias_ir[oc], bu = bias_iu[oc], bc = bias_ic[oc];
      #pragma unroll
      for (int i = 0; i < 4; i++){
        if (wok[i]){
          size_t idx = (size_t)erow[i]*F_ + oc;
          float zr  = Y0[idx] + Y1[idx] + br + dr[i];
          float zu  = Y2[idx] + Y3[idx] + bu + du[i];
          float zic = Y4[idx] + bc + dic[i];
          float zrc = Y5[idx] + drc[i];
          float cv  = carry[idx];
          float rr = 1.f/(1.f+__expf(-zr));
          float uu = 1.f/(1.f+__expf(-zu));
          float a = zic + rr*zrc;
          float ee = __expf(-2.f*fabsf(a));
          float cand = copysignf((1.f-ee)/(1.f+ee), a);
          out[idx] = (1.f-uu)*cand + uu*cv;
        }
      }
    }
  }
}

extern "C" void kernel_launch(void* const* d_in, const int* in_sizes, int n_in,
                              void* d_out, int out_size, void* d_ws, size_t ws_size,
                              hipStream_t stream){
  const float* carry   = (const float*)d_in[0];
  const float* x       = (const float*)d_in[1];
  const int*   ids     = (const int*)d_in[2];
  const float* w_ir    = (const float*)d_in[3];
  const float* bias_ir = (const float*)d_in[4];
  const float* la_ir   = (const float*)d_in[5];
  const float* lb_ir   = (const float*)d_in[6];
  const float* w_iu    = (const float*)d_in[7];
  const float* bias_iu = (const float*)d_in[8];
  const float* la_iu   = (const float*)d_in[9];
  const float* lb_iu   = (const float*)d_in[10];
  const float* w_ic    = (const float*)d_in[11];
  const float* bias_ic = (const float*)d_in[12];
  const float* la_ic   = (const float*)d_in[13];
  const float* lb_ic   = (const float*)d_in[14];
  const float* w_rr    = (const float*)d_in[15];
  const float* la_rr   = (const float*)d_in[16];
  const float* lb_rr   = (const float*)d_in[17];
  const float* w_ru    = (const float*)d_in[18];
  const float* la_ru   = (const float*)d_in[19];
  const float* lb_ru   = (const float*)d_in[20];
  const float* w_rc    = (const float*)d_in[21];
  const float* la_rc   = (const float*)d_in[22];
  const float* lb_rc   = (const float*)d_in[23];

  char* ws = (char*)d_ws;
  unsigned short* XC     = (unsigned short*)(ws + 0);          // 8 MiB
  unsigned short* Wt_all = (unsigned short*)(ws + 8388608);    // 12 MiB (6 x 2 MiB)
  float* Yall = (float*)(ws + 20971520);                       // 48 MiB (6 x 8 MiB)
  float* low  = (float*)(ws + 71303168);                       // 768 KiB
  int* starts = (int*)(ws + 72089600);
  int* order  = (int*)(ws + 72090624);

  cast_xc_kernel<<<dim3(2048), dim3(256), 0, stream>>>(x, carry, XC);
  wcast_kernel<<<dim3(256, 6), dim3(256), 0, stream>>>(w_ir, w_rr, w_iu, w_ru, w_ic, w_rc,
                                                       Wt_all);
  bucket_kernel<<<dim3(1), dim3(256), 0, stream>>>(ids, starts, order);
  low_kernel<<<dim3(64, 6), dim3(256), 0, stream>>>(XC, la_ir, la_iu, la_ic,
                                                    la_rr, la_ru, la_rc, starts, order, low);
  gemm_kernel<<<dim3(128, 6), dim3(256), 0, stream>>>(XC, Wt_all, Yall);
  delta_final_kernel<<<dim3(64, 8), dim3(256), 0, stream>>>(carry, bias_ir, bias_iu, bias_ic,
                                                            lb_ir, lb_rr, lb_iu, lb_ru,
                                                            lb_ic, lb_rc,
                                                            starts, order, low, Yall,
                                                            (float*)d_out);
}

// Round 6
// 101.514 us; speedup vs baseline: 1.2799x; 1.0118x over previous
//
#include <hip/hip_runtime.h>
#include <stdint.h>

#define B_  2048
#define D_  1024
#define F_  1024
#define S_  64
#define R_  16

typedef __attribute__((ext_vector_type(8))) short  s16x8;
typedef __attribute__((ext_vector_type(4))) unsigned short u16x4;
typedef __attribute__((ext_vector_type(8))) unsigned short u16x8;
typedef __attribute__((ext_vector_type(4))) float  f32x4;

__device__ __forceinline__ unsigned short f2b(float f){
  unsigned u = __float_as_uint(f);
  u = u + 0x7fffu + ((u >> 16) & 1u);   // RNE to bf16
  return (unsigned short)(u >> 16);
}
__device__ __forceinline__ float b2f(unsigned short s){
  return __uint_as_float(((unsigned)s) << 16);
}

__device__ __forceinline__ void gload16(const void* g, void* l){
  __builtin_amdgcn_global_load_lds((const __attribute__((address_space(1))) unsigned int*)g,
                                   (__attribute__((address_space(3))) unsigned int*)l, 16, 0, 0);
}

// ---------------- kernel 1a: XC = [bf16(x) | bf16(carry)]  (B x 2048) ----------------
__global__ void cast_xc_kernel(const float* __restrict__ x, const float* __restrict__ carry,
                               unsigned short* __restrict__ XC){
  int i = blockIdx.x * blockDim.x + threadIdx.x;
  if (i >= B_ * (D_/4)) return;
  int b = i >> 8;
  int j = (i & 255) * 4;
  float4 xv = *(const float4*)&x[(size_t)b*D_ + j];
  float4 cv = *(const float4*)&carry[(size_t)b*F_ + j];
  u16x4 xs, cs;
  xs[0]=f2b(xv.x); xs[1]=f2b(xv.y); xs[2]=f2b(xv.z); xs[3]=f2b(xv.w);
  cs[0]=f2b(cv.x); cs[1]=f2b(cv.y); cs[2]=f2b(cv.z); cs[3]=f2b(cv.w);
  *(u16x4*)&XC[(size_t)b*2048 + j]        = xs;
  *(u16x4*)&XC[(size_t)b*2048 + 1024 + j] = cs;
}

// ---------------- kernel 1b: transpose-cast 6 weights into Wt_all[u][n][k] bf16 -----------
// unit order: 0=ir(x), 1=rr(c), 2=iu(x), 3=ru(c), 4=ic(x), 5=rc(c)
__global__ void wcast_kernel(const float* __restrict__ w_ir, const float* __restrict__ w_rr,
                             const float* __restrict__ w_iu, const float* __restrict__ w_ru,
                             const float* __restrict__ w_ic, const float* __restrict__ w_rc,
                             unsigned short* __restrict__ Wt_all){
  int u = blockIdx.y;
  const float* W;
  switch(u){ case 0: W=w_ir; break; case 1: W=w_rr; break; case 2: W=w_iu; break;
             case 3: W=w_ru; break; case 4: W=w_ic; break; default: W=w_rc; break; }
  unsigned short* O = Wt_all + (size_t)u * (1024*1024);
  __shared__ unsigned short T[64][72];   // row stride 144B (9*16B)
  int t = threadIdx.x;
  int n0 = (blockIdx.x & 15) * 64;
  int k0 = (blockIdx.x >> 4) * 64;
  int c4 = (t & 15) * 4;
  int kk = t >> 4;
  #pragma unroll
  for (int i = 0; i < 4; i++){
    int k = kk + i*16;
    float4 v = *(const float4*)&W[(size_t)(k0+k)*F_ + n0 + c4];
    T[c4+0][k] = f2b(v.x); T[c4+1][k] = f2b(v.y); T[c4+2][k] = f2b(v.z); T[c4+3][k] = f2b(v.w);
  }
  __syncthreads();
  int n = t >> 2, ch = (t & 3) * 16;
  u16x8 a = *(const u16x8*)&T[n][ch];
  u16x8 b = *(const u16x8*)&T[n][ch+8];
  *(u16x8*)&O[(size_t)(n0+n)*1024 + k0 + ch]     = a;
  *(u16x8*)&O[(size_t)(n0+n)*1024 + k0 + ch + 8] = b;
}

// ---------------- kernel 2: bucket examples by adapter id ----------------
__global__ void bucket_kernel(const int* __restrict__ ids, int* __restrict__ starts,
                              int* __restrict__ order){
  __shared__ int cnt[S_]; __shared__ int off[S_+1]; __shared__ int cur[S_];
  int t = threadIdx.x;
  if (t < S_) cnt[t] = 0;
  __syncthreads();
  for (int b = t; b < B_; b += 256) atomicAdd(&cnt[ids[b]], 1);
  __syncthreads();
  if (t == 0){ off[0] = 0; for (int s2 = 0; s2 < S_; s2++) off[s2+1] = off[s2] + cnt[s2]; }
  __syncthreads();
  if (t < S_) cur[t] = off[t];
  __syncthreads();
  for (int b = t; b < B_; b += 256){ int p = atomicAdd(&cur[ids[b]], 1); order[p] = b; }
  if (t < S_+1) starts[t] = off[t];
}

// ---------------- kernel 3: low[g][b][r] = XC[b, gslice] . la_g[id[b]][:,r]  (MFMA) ------
// g order: 0=ir, 1=iu, 2=ic, 3=rr, 4=ru, 5=rc
__global__ __launch_bounds__(256) void low_kernel(
    const unsigned short* __restrict__ XC,
    const float* __restrict__ la_ir, const float* __restrict__ la_iu,
    const float* __restrict__ la_ic, const float* __restrict__ la_rr,
    const float* __restrict__ la_ru, const float* __restrict__ la_rc,
    const int* __restrict__ starts, const int* __restrict__ order,
    float* __restrict__ low){
  int s = blockIdx.x, g = blockIdx.y;
  const float* la;
  switch(g){ case 0: la=la_ir; break; case 1: la=la_iu; break; case 2: la=la_ic; break;
             case 3: la=la_rr; break; case 4: la=la_ru; break; default: la=la_rc; break; }
  int kofs = (g < 3) ? 0 : 1024;
  la += (size_t)s * D_ * R_;
  __shared__ unsigned short LA[16 * 1032];   // [r][d], pad 8
  int t = threadIdx.x;
  for (int i4 = t; i4 < D_*R_/4; i4 += 256){
    float4 v = *(const float4*)&la[i4*4];
    int d = i4 >> 2, r0 = (i4 & 3) * 4;
    LA[(r0+0)*1032 + d] = f2b(v.x);
    LA[(r0+1)*1032 + d] = f2b(v.y);
    LA[(r0+2)*1032 + d] = f2b(v.z);
    LA[(r0+3)*1032 + d] = f2b(v.w);
  }
  __syncthreads();
  int start = starts[s], cnt = starts[s+1] - start;
  if (cnt == 0) return;
  int lane = t & 63, wave = t >> 6;
  int l15 = lane & 15, kq = (lane >> 4) * 8;
  int ntiles = (cnt + 15) >> 4;
  for (int mt = wave*2; mt < ntiles; mt += 8){
    bool two = (mt + 1 < ntiles);
    int m0 = mt*16 + l15;       if (m0 >= cnt) m0 = cnt - 1;
    int m1 = (mt+1)*16 + l15;   if (m1 >= cnt) m1 = cnt - 1;
    int e0 = order[start + m0];
    int e1 = two ? order[start + m1] : e0;
    const unsigned short* A0 = XC + (size_t)e0*2048 + kofs + kq;
    const unsigned short* A1 = XC + (size_t)e1*2048 + kofs + kq;
    const unsigned short* Bp = &LA[l15*1032 + kq];
    f32x4 acc0 = {}, acc1 = {};
    #pragma unroll 4
    for (int kt = 0; kt < 1024; kt += 32){
      s16x8 a0 = *(const s16x8*)(A0 + kt);
      s16x8 a1 = *(const s16x8*)(A1 + kt);
      s16x8 b  = *(const s16x8*)(Bp + kt);
      acc0 = __builtin_amdgcn_mfma_f32_16x16x32_bf16(a0, b, acc0, 0, 0, 0);
      acc1 = __builtin_amdgcn_mfma_f32_16x16x32_bf16(a1, b, acc1, 0, 0, 0);
    }
    int rowb = (lane >> 4) * 4;
    #pragma unroll
    for (int i = 0; i < 4; i++){
      int m = mt*16 + rowb + i;
      if (m < cnt){
        int e = order[start + m];
        low[((size_t)g*B_ + e)*R_ + l15] = acc0[i];
      }
    }
    if (two){
      #pragma unroll
      for (int i = 0; i < 4; i++){
        int m = (mt+1)*16 + rowb + i;
        if (m < cnt){
          int e = order[start + m];
          low[((size_t)g*B_ + e)*R_ + l15] = acc1[i];
        }
      }
    }
  }
}

// ---------------- kernel 4: MFMA GEMM — 3-buffer rotating LDS, counted vmcnt pipeline -----
// Per K-step t: s_waitcnt vmcnt(4) [own stage-t done, stage-t+1 in flight] -> s_barrier
// [all waves' stage-t done] -> ds_read+MFMA on buf[t%3] -> STAGE(t+2) into buf[(t+2)%3]
// (= buf[(t-1)%3]; all its readers finished before this barrier). vmcnt never 0 in loop.
// LDS k-slot swizzle (kept from r5): phys slot p of row r holds logical slot p^((r>>1)&3).
__global__ __launch_bounds__(256, 3) void gemm_kernel(
    const unsigned short* __restrict__ XC,
    const unsigned short* __restrict__ Wt_all,
    float* __restrict__ Yall){
  int u = blockIdx.y;
  const unsigned short* Wt = Wt_all + (size_t)u * (1024*1024);
  float* Y = Yall + (size_t)u * ((size_t)B_ * F_);
  int kofs = (u & 1) << 10;

  __shared__ unsigned short As[3][128*32];
  __shared__ unsigned short Bs[3][128*32];

  int t = threadIdx.x;
  int lane = t & 63, wave = t >> 6;
  int mt = blockIdx.x >> 3, nt = blockIdx.x & 7;
  int row0 = mt * 128, col0 = nt * 128;
  int wrow = (wave >> 1) * 64, wcol = (wave & 1) * 64;

  int arow = t >> 2;
  int achk = ((t & 3) ^ ((t >> 3) & 3)) * 8;   // swizzled source k-slot

  const unsigned short* Ab  = XC + (size_t)(row0 + arow) * 2048 + kofs + achk;
  const unsigned short* Ab2 = Ab + (size_t)64 * 2048;
  const unsigned short* Bb  = Wt + (size_t)(col0 + arow) * 1024 + achk;
  const unsigned short* Bb2 = Bb + (size_t)64 * 1024;

  int l15 = lane & 15;
  int kof = (((lane >> 4) ^ ((l15 >> 1) & 3)) * 8);   // swizzled read slot
  f32x4 acc[4][4] = {};

  // prologue: stage tiles 0 and 1
  gload16(Ab,      &As[0][t*8]);  gload16(Ab2,      &As[0][2048 + t*8]);
  gload16(Bb,      &Bs[0][t*8]);  gload16(Bb2,      &Bs[0][2048 + t*8]);
  gload16(Ab + 32, &As[1][t*8]);  gload16(Ab2 + 32, &As[1][2048 + t*8]);
  gload16(Bb + 32, &Bs[1][t*8]);  gload16(Bb2 + 32, &Bs[1][2048 + t*8]);

  int cur = 0;
  for (int tt = 0; tt < 31; ++tt){
    asm volatile("s_waitcnt vmcnt(4)" ::: "memory");
    __builtin_amdgcn_s_barrier();
    asm volatile("" ::: "memory");
    s16x8 af[4], bfr[4];
    #pragma unroll
    for (int m = 0; m < 4; m++)
      af[m] = *(const s16x8*)&As[cur][(wrow + m*16 + l15)*32 + kof];
    #pragma unroll
    for (int n = 0; n < 4; n++)
      bfr[n] = *(const s16x8*)&Bs[cur][(wcol + n*16 + l15)*32 + kof];
    __builtin_amdgcn_s_setprio(1);
    #pragma unroll
    for (int m = 0; m < 4; m++){
      #pragma unroll
      for (int n = 0; n < 4; n++){
        acc[m][n] = __builtin_amdgcn_mfma_f32_16x16x32_bf16(af[m], bfr[n], acc[m][n], 0, 0, 0);
      }
    }
    __builtin_amdgcn_s_setprio(0);
    if (tt < 30){
      int nb = cur + 2; if (nb >= 3) nb -= 3;
      int kt = (tt + 2) * 32;
      gload16(Ab  + kt, &As[nb][t*8]);  gload16(Ab2 + kt, &As[nb][2048 + t*8]);
      gload16(Bb  + kt, &Bs[nb][t*8]);  gload16(Bb2 + kt, &Bs[nb][2048 + t*8]);
    }
    cur = cur + 1; if (cur >= 3) cur -= 3;
  }
  // final tile (tt=31, buf cur): drain all
  asm volatile("s_waitcnt vmcnt(0)" ::: "memory");
  __builtin_amdgcn_s_barrier();
  asm volatile("" ::: "memory");
  {
    s16x8 af[4], bfr[4];
    #pragma unroll
    for (int m = 0; m < 4; m++)
      af[m] = *(const s16x8*)&As[cur][(wrow + m*16 + l15)*32 + kof];
    #pragma unroll
    for (int n = 0; n < 4; n++)
      bfr[n] = *(const s16x8*)&Bs[cur][(wcol + n*16 + l15)*32 + kof];
    #pragma unroll
    for (int m = 0; m < 4; m++){
      #pragma unroll
      for (int n = 0; n < 4; n++){
        acc[m][n] = __builtin_amdgcn_mfma_f32_16x16x32_bf16(af[m], bfr[n], acc[m][n], 0, 0, 0);
      }
    }
  }

  int orow = row0 + wrow + (lane >> 4) * 4;
  int ocol = col0 + wcol + l15;
  #pragma unroll
  for (int m = 0; m < 4; m++){
    #pragma unroll
    for (int n = 0; n < 4; n++){
      #pragma unroll
      for (int i = 0; i < 4; i++){
        Y[(size_t)(orow + m*16 + i) * F_ + ocol + n*16] = acc[m][n][i];
      }
    }
  }
}

// ---------------- kernel 5: fused MFMA delta + GRU gates + output (bucketed) ----------------
__global__ __launch_bounds__(256) void delta_final_kernel(
    const float* __restrict__ carry,
    const float* __restrict__ bias_ir, const float* __restrict__ bias_iu,
    const float* __restrict__ bias_ic,
    const float* __restrict__ lb_ir, const float* __restrict__ lb_rr,
    const float* __restrict__ lb_iu, const float* __restrict__ lb_ru,
    const float* __restrict__ lb_ic, const float* __restrict__ lb_rc,
    const int* __restrict__ starts, const int* __restrict__ order,
    const float* __restrict__ low, const float* __restrict__ Yall,
    float* __restrict__ out){
  int s = blockIdx.x;
  int c0 = blockIdx.y * 128;
  __shared__ unsigned short Bs[3 * 128 * 40];   // 3 stacked [col][k0..31], stride 40
  int t = threadIdx.x;
  const float* lbp[6] = {lb_ir, lb_rr, lb_iu, lb_ru, lb_ic, lb_rc};
  #pragma unroll
  for (int j = 0; j < 6; j++){
    const float* lb = lbp[j] + (size_t)s * R_ * F_;
    unsigned short* Bj = &Bs[(j >> 1)*5120 + (j & 1)*16];
    #pragma unroll
    for (int it = 0; it < 2; it++){
      int idx = t + it*256;
      int r = idx >> 5, c4 = (idx & 31) * 4;
      float4 v = *(const float4*)&lb[(size_t)r*F_ + c0 + c4];
      Bj[(c4+0)*40 + r] = f2b(v.x);
      Bj[(c4+1)*40 + r] = f2b(v.y);
      Bj[(c4+2)*40 + r] = f2b(v.z);
      Bj[(c4+3)*40 + r] = f2b(v.w);
    }
  }
  __syncthreads();
  int start = starts[s], cnt = starts[s+1] - start;
  if (cnt == 0) return;
  int lane = t & 63, wave = t >> 6;
  int l15 = lane & 15, kq = (lane >> 4) * 8;   // 0,8,16,24
  int ntiles = (cnt + 15) >> 4;
  const float* Y0 = Yall + 0*(size_t)B_*F_;
  const float* Y1 = Yall + 1*(size_t)B_*F_;
  const float* Y2 = Yall + 2*(size_t)B_*F_;
  const float* Y3 = Yall + 3*(size_t)B_*F_;
  const float* Y4 = Yall + 4*(size_t)B_*F_;
  const float* Y5 = Yall + 5*(size_t)B_*F_;
  int k8 = kq & 15; bool hi = (kq >= 16);
  // work items: (m-tile, cf-half) pairs for wave balance at small cnt
  for (int pt = wave; pt < ntiles*2; pt += 4){
    int mt = pt >> 1, cf0 = (pt & 1) * 4;
    int m = mt*16 + l15; if (m >= cnt) m = cnt - 1;
    int e = order[start + m];
    s16x8 a_r, a_u, a_c1 = {}, a_c2 = {};
    {
      const float* p = &low[((size_t)(hi ? 3 : 0)*B_ + e)*R_ + k8];
      float4 v0 = *(const float4*)p, v1 = *(const float4*)(p+4);
      a_r[0]=f2b(v0.x); a_r[1]=f2b(v0.y); a_r[2]=f2b(v0.z); a_r[3]=f2b(v0.w);
      a_r[4]=f2b(v1.x); a_r[5]=f2b(v1.y); a_r[6]=f2b(v1.z); a_r[7]=f2b(v1.w);
    }
    {
      const float* p = &low[((size_t)(hi ? 4 : 1)*B_ + e)*R_ + k8];
      float4 v0 = *(const float4*)p, v1 = *(const float4*)(p+4);
      a_u[0]=f2b(v0.x); a_u[1]=f2b(v0.y); a_u[2]=f2b(v0.z); a_u[3]=f2b(v0.w);
      a_u[4]=f2b(v1.x); a_u[5]=f2b(v1.y); a_u[6]=f2b(v1.z); a_u[7]=f2b(v1.w);
    }
    if (!hi){
      const float* p = &low[((size_t)2*B_ + e)*R_ + k8];
      float4 v0 = *(const float4*)p, v1 = *(const float4*)(p+4);
      a_c1[0]=f2b(v0.x); a_c1[1]=f2b(v0.y); a_c1[2]=f2b(v0.z); a_c1[3]=f2b(v0.w);
      a_c1[4]=f2b(v1.x); a_c1[5]=f2b(v1.y); a_c1[6]=f2b(v1.z); a_c1[7]=f2b(v1.w);
    } else {
      const float* p = &low[((size_t)5*B_ + e)*R_ + k8];
      float4 v0 = *(const float4*)p, v1 = *(const float4*)(p+4);
      a_c2[0]=f2b(v0.x); a_c2[1]=f2b(v0.y); a_c2[2]=f2b(v0.z); a_c2[3]=f2b(v0.w);
      a_c2[4]=f2b(v1.x); a_c2[5]=f2b(v1.y); a_c2[6]=f2b(v1.z); a_c2[7]=f2b(v1.w);
    }
    int rowb = (lane >> 4) * 4;
    int erow[4]; bool wok[4];
    #pragma unroll
    for (int i = 0; i < 4; i++){
      int mm = mt*16 + rowb + i;
      wok[i] = (mm < cnt);
      erow[i] = order[start + (wok[i] ? mm : cnt - 1)];
    }
    #pragma unroll
    for (int cf = cf0; cf < cf0 + 4; cf++){
      int col = cf*16 + l15;
      s16x8 b_r = *(const s16x8*)&Bs[0*5120 + col*40 + kq];
      s16x8 b_u = *(const s16x8*)&Bs[1*5120 + col*40 + kq];
      s16x8 b_c = *(const s16x8*)&Bs[2*5120 + col*40 + kq];
      f32x4 zero = {};
      f32x4 dr  = __builtin_amdgcn_mfma_f32_16x16x32_bf16(a_r,  b_r, zero, 0, 0, 0);
      f32x4 du  = __builtin_amdgcn_mfma_f32_16x16x32_bf16(a_u,  b_u, zero, 0, 0, 0);
      f32x4 dic = __builtin_amdgcn_mfma_f32_16x16x32_bf16(a_c1, b_c, zero, 0, 0, 0);
      f32x4 drc = __builtin_amdgcn_mfma_f32_16x16x32_bf16(a_c2, b_c, zero, 0, 0, 0);
      int oc = c0 + col;
      float br = bias_ir[oc], bu = bias_iu[oc], bc = bias_ic[oc];
      #pragma unroll
      for (int i = 0; i < 4; i++){
        if (wok[i]){
          size_t idx = (size_t)erow[i]*F_ + oc;
          float zr  = Y0[idx] + Y1[idx] + br + dr[i];
          float zu  = Y2[idx] + Y3[idx] + bu + du[i];
          float zic = Y4[idx] + bc + dic[i];
          float zrc = Y5[idx] + drc[i];
          float cv  = carry[idx];
          float rr = 1.f/(1.f+__expf(-zr));
          float uu = 1.f/(1.f+__expf(-zu));
          float a = zic + rr*zrc;
          float ee = __expf(-2.f*fabsf(a));
          float cand = copysignf((1.f-ee)/(1.f+ee), a);
          out[idx] = (1.f-uu)*cand + uu*cv;
        }
      }
    }
  }
}

extern "C" void kernel_launch(void* const* d_in, const int* in_sizes, int n_in,
                              void* d_out, int out_size, void* d_ws, size_t ws_size,
                              hipStream_t stream){
  const float* carry   = (const float*)d_in[0];
  const float* x       = (const float*)d_in[1];
  const int*   ids     = (const int*)d_in[2];
  const float* w_ir    = (const float*)d_in[3];
  const float* bias_ir = (const float*)d_in[4];
  const float* la_ir   = (const float*)d_in[5];
  const float* lb_ir   = (const float*)d_in[6];
  const float* w_iu    = (const float*)d_in[7];
  const float* bias_iu = (const float*)d_in[8];
  const float* la_iu   = (const float*)d_in[9];
  const float* lb_iu   = (const float*)d_in[10];
  const float* w_ic    = (const float*)d_in[11];
  const float* bias_ic = (const float*)d_in[12];
  const float* la_ic   = (const float*)d_in[13];
  const float* lb_ic   = (const float*)d_in[14];
  const float* w_rr    = (const float*)d_in[15];
  const float* la_rr   = (const float*)d_in[16];
  const float* lb_rr   = (const float*)d_in[17];
  const float* w_ru    = (const float*)d_in[18];
  const float* la_ru   = (const float*)d_in[19];
  const float* lb_ru   = (const float*)d_in[20];
  const float* w_rc    = (const float*)d_in[21];
  const float* la_rc   = (const float*)d_in[22];
  const float* lb_rc   = (const float*)d_in[23];

  char* ws = (char*)d_ws;
  unsigned short* XC     = (unsigned short*)(ws + 0);          // 8 MiB
  unsigned short* Wt_all = (unsigned short*)(ws + 8388608);    // 12 MiB (6 x 2 MiB)
  float* Yall = (float*)(ws + 20971520);                       // 48 MiB (6 x 8 MiB)
  float* low  = (float*)(ws + 71303168);                       // 768 KiB
  int* starts = (int*)(ws + 72089600);
  int* order  = (int*)(ws + 72090624);

  cast_xc_kernel<<<dim3(2048), dim3(256), 0, stream>>>(x, carry, XC);
  wcast_kernel<<<dim3(256, 6), dim3(256), 0, stream>>>(w_ir, w_rr, w_iu, w_ru, w_ic, w_rc,
                                                       Wt_all);
  bucket_kernel<<<dim3(1), dim3(256), 0, stream>>>(ids, starts, order);
  low_kernel<<<dim3(64, 6), dim3(256), 0, stream>>>(XC, la_ir, la_iu, la_ic,
                                                    la_rr, la_ru, la_rc, starts, order, low);
  gemm_kernel<<<dim3(128, 6), dim3(256), 0, stream>>>(XC, Wt_all, Yall);
  delta_final_kernel<<<dim3(64, 8), dim3(256), 0, stream>>>(carry, bias_ir, bias_iu, bias_ic,
                                                            lb_ir, lb_rr, lb_iu, lb_ru,
                                                            lb_ic, lb_rc,
                                                            starts, order, low, Yall,
                                                            (float*)d_out);
}

// Round 7
// 90.903 us; speedup vs baseline: 1.4292x; 1.1167x over previous
//
#include <hip/hip_runtime.h>
#include <stdint.h>

#define B_  2048
#define D_  1024
#define F_  1024
#define S_  64
#define R_  16

typedef __attribute__((ext_vector_type(8))) short  s16x8;
typedef __attribute__((ext_vector_type(4))) unsigned short u16x4;
typedef __attribute__((ext_vector_type(8))) unsigned short u16x8;
typedef __attribute__((ext_vector_type(4))) float  f32x4;

__device__ __forceinline__ unsigned short f2b(float f){
  unsigned u = __float_as_uint(f);
  u = u + 0x7fffu + ((u >> 16) & 1u);   // RNE to bf16
  return (unsigned short)(u >> 16);
}
__device__ __forceinline__ float b2f(unsigned short s){
  return __uint_as_float(((unsigned)s) << 16);
}

__device__ __forceinline__ void gload16(const void* g, void* l){
  __builtin_amdgcn_global_load_lds((const __attribute__((address_space(1))) unsigned int*)g,
                                   (__attribute__((address_space(3))) unsigned int*)l, 16, 0, 0);
}

// Wt_all element offsets: W0t(ir+rr,K2048)=0, W1t(iu+ru,K2048)=2M, W2t(ic,K1024)=4M, W3t(rc)=5M
#define W0OFF 0
#define W1OFF 2097152
#define W2OFF 4194304
#define W3OFF 5242880

// ---------------- kernel 1: fused prep = cast_xc | wcast | bucket (block-partitioned) -----
// blocks [0,2048): XC cast; [2048,3584): weight transpose-cast (256/source); 3584: bucket
__global__ __launch_bounds__(256) void prep_kernel(
    const float* __restrict__ x, const float* __restrict__ carry,
    unsigned short* __restrict__ XC,
    const float* __restrict__ w_ir, const float* __restrict__ w_rr,
    const float* __restrict__ w_iu, const float* __restrict__ w_ru,
    const float* __restrict__ w_ic, const float* __restrict__ w_rc,
    unsigned short* __restrict__ Wt_all,
    const int* __restrict__ ids, int* __restrict__ starts, int* __restrict__ order){
  int bx = blockIdx.x;
  int t = threadIdx.x;
  if (bx < 2048){
    int i = bx * 256 + t;
    int b = i >> 8;
    int j = (i & 255) * 4;
    float4 xv = *(const float4*)&x[(size_t)b*D_ + j];
    float4 cv = *(const float4*)&carry[(size_t)b*F_ + j];
    u16x4 xs, cs;
    xs[0]=f2b(xv.x); xs[1]=f2b(xv.y); xs[2]=f2b(xv.z); xs[3]=f2b(xv.w);
    cs[0]=f2b(cv.x); cs[1]=f2b(cv.y); cs[2]=f2b(cv.z); cs[3]=f2b(cv.w);
    *(u16x4*)&XC[(size_t)b*2048 + j]        = xs;
    *(u16x4*)&XC[(size_t)b*2048 + 1024 + j] = cs;
    return;
  }
  if (bx < 3584){
    int wb = bx - 2048;
    int g = wb >> 8, xb = wb & 255;
    const float* W; unsigned short* O; int st, ko;
    switch(g){
      case 0:  W=w_ir; O=Wt_all+W0OFF; st=2048; ko=0;    break;
      case 1:  W=w_rr; O=Wt_all+W0OFF; st=2048; ko=1024; break;
      case 2:  W=w_iu; O=Wt_all+W1OFF; st=2048; ko=0;    break;
      case 3:  W=w_ru; O=Wt_all+W1OFF; st=2048; ko=1024; break;
      case 4:  W=w_ic; O=Wt_all+W2OFF; st=1024; ko=0;    break;
      default: W=w_rc; O=Wt_all+W3OFF; st=1024; ko=0;    break;
    }
    __shared__ unsigned short T[64][72];   // row stride 144B (9*16B)
    int n0 = (xb & 15) * 64;
    int k0 = (xb >> 4) * 64;
    int c4 = (t & 15) * 4;
    int kk = t >> 4;
    #pragma unroll
    for (int i = 0; i < 4; i++){
      int k = kk + i*16;
      float4 v = *(const float4*)&W[(size_t)(k0+k)*F_ + n0 + c4];
      T[c4+0][k] = f2b(v.x); T[c4+1][k] = f2b(v.y); T[c4+2][k] = f2b(v.z); T[c4+3][k] = f2b(v.w);
    }
    __syncthreads();
    int n = t >> 2, ch = (t & 3) * 16;
    u16x8 a = *(const u16x8*)&T[n][ch];
    u16x8 b = *(const u16x8*)&T[n][ch+8];
    *(u16x8*)&O[(size_t)(n0+n)*st + ko + k0 + ch]     = a;
    *(u16x8*)&O[(size_t)(n0+n)*st + ko + k0 + ch + 8] = b;
    return;
  }
  // bucket
  __shared__ int cnt[S_]; __shared__ int off[S_+1]; __shared__ int cur[S_];
  if (t < S_) cnt[t] = 0;
  __syncthreads();
  for (int b = t; b < B_; b += 256) atomicAdd(&cnt[ids[b]], 1);
  __syncthreads();
  if (t == 0){ off[0] = 0; for (int s2 = 0; s2 < S_; s2++) off[s2+1] = off[s2] + cnt[s2]; }
  __syncthreads();
  if (t < S_) cur[t] = off[t];
  __syncthreads();
  for (int b = t; b < B_; b += 256){ int p = atomicAdd(&cur[ids[b]], 1); order[p] = b; }
  if (t < S_+1) starts[t] = off[t];
}

// ---------------- kernel 2: co-dispatched low (blocks 0..383) + GEMM (blocks 384..895) ----
// low:  low[g][b][r] = XC[b, gslice] . la_g[id[b]][:,r]   (g: 0=ir 1=iu 2=ic | 3=rr 4=ru 5=rc)
// gemm: Y[u] = XC[:, ks(u)] @ Wt[u]^T  (u0: K2048 ir+rr, u1: K2048 iu+ru, u2: K1024 ic(x),
//       u3: K1024 rc(carry));  3-buffer rotating LDS, counted vmcnt(4), k-slot swizzle.
__global__ __launch_bounds__(256, 3) void gemm_low_kernel(
    const unsigned short* __restrict__ XC,
    const unsigned short* __restrict__ Wt_all,
    float* __restrict__ Yall,
    const float* __restrict__ la_ir, const float* __restrict__ la_iu,
    const float* __restrict__ la_ic, const float* __restrict__ la_rr,
    const float* __restrict__ la_ru, const float* __restrict__ la_rc,
    const int* __restrict__ starts, const int* __restrict__ order,
    float* __restrict__ low){
  __shared__ __align__(16) unsigned short smem[24576];   // 48 KB overlay
  int t = threadIdx.x;
  int bx = blockIdx.x;

  if (bx < 384){
    // ---- low path ----
    int s = bx & 63, g = bx / 64;
    const float* la;
    switch(g){ case 0: la=la_ir; break; case 1: la=la_iu; break; case 2: la=la_ic; break;
               case 3: la=la_rr; break; case 4: la=la_ru; break; default: la=la_rc; break; }
    int kofs = (g < 3) ? 0 : 1024;
    la += (size_t)s * D_ * R_;
    unsigned short* LA = smem;             // [r][d] 16 x 1032 (pad 8)
    for (int i4 = t; i4 < D_*R_/4; i4 += 256){
      float4 v = *(const float4*)&la[i4*4];
      int d = i4 >> 2, r0 = (i4 & 3) * 4;
      LA[(r0+0)*1032 + d] = f2b(v.x);
      LA[(r0+1)*1032 + d] = f2b(v.y);
      LA[(r0+2)*1032 + d] = f2b(v.z);
      LA[(r0+3)*1032 + d] = f2b(v.w);
    }
    __syncthreads();
    int start = starts[s], cnt = starts[s+1] - start;
    if (cnt == 0) return;
    int lane = t & 63, wave = t >> 6;
    int l15 = lane & 15, kq = (lane >> 4) * 8;
    int ntiles = (cnt + 15) >> 4;
    for (int mt = wave*2; mt < ntiles; mt += 8){
      bool two = (mt + 1 < ntiles);
      int m0 = mt*16 + l15;       if (m0 >= cnt) m0 = cnt - 1;
      int m1 = (mt+1)*16 + l15;   if (m1 >= cnt) m1 = cnt - 1;
      int e0 = order[start + m0];
      int e1 = two ? order[start + m1] : e0;
      const unsigned short* A0 = XC + (size_t)e0*2048 + kofs + kq;
      const unsigned short* A1 = XC + (size_t)e1*2048 + kofs + kq;
      const unsigned short* Bp = &LA[l15*1032 + kq];
      f32x4 acc0 = {}, acc1 = {};
      #pragma unroll 4
      for (int kt = 0; kt < 1024; kt += 32){
        s16x8 a0 = *(const s16x8*)(A0 + kt);
        s16x8 a1 = *(const s16x8*)(A1 + kt);
        s16x8 b  = *(const s16x8*)(Bp + kt);
        acc0 = __builtin_amdgcn_mfma_f32_16x16x32_bf16(a0, b, acc0, 0, 0, 0);
        acc1 = __builtin_amdgcn_mfma_f32_16x16x32_bf16(a1, b, acc1, 0, 0, 0);
      }
      int rowb = (lane >> 4) * 4;
      #pragma unroll
      for (int i = 0; i < 4; i++){
        int m = mt*16 + rowb + i;
        if (m < cnt){
          int e = order[start + m];
          low[((size_t)g*B_ + e)*R_ + l15] = acc0[i];
        }
      }
      if (two){
        #pragma unroll
        for (int i = 0; i < 4; i++){
          int m = (mt+1)*16 + rowb + i;
          if (m < cnt){
            int e = order[start + m];
            low[((size_t)g*B_ + e)*R_ + l15] = acc1[i];
          }
        }
      }
    }
    return;
  }

  // ---- gemm path ----
  int bid = bx - 384;
  int u = bid >> 7;                 // 128 blocks/unit
  int tile = bid & 127;
  int K = (u < 2) ? 2048 : 1024;
  int kofs = (u == 3) ? 1024 : 0;
  const size_t uoffs[4] = {W0OFF, W1OFF, W2OFF, W3OFF};
  const unsigned short* Wt = Wt_all + uoffs[u];
  float* Y = Yall + (size_t)u * ((size_t)B_ * F_);

  unsigned short (*As)[4096] = (unsigned short(*)[4096])smem;            // [3][4096]
  unsigned short (*Bs)[4096] = (unsigned short(*)[4096])(smem + 12288);  // [3][4096]

  int lane = t & 63, wave = t >> 6;
  int mt = tile >> 3, nt = tile & 7;
  int row0 = mt * 128, col0 = nt * 128;
  int wrow = (wave >> 1) * 64, wcol = (wave & 1) * 64;

  int arow = t >> 2;
  int achk = ((t & 3) ^ ((t >> 3) & 3)) * 8;   // swizzled source k-slot

  const unsigned short* Ab  = XC + (size_t)(row0 + arow) * 2048 + kofs + achk;
  const unsigned short* Ab2 = Ab + (size_t)64 * 2048;
  const unsigned short* Bb  = Wt + (size_t)(col0 + arow) * K + achk;
  const unsigned short* Bb2 = Bb + (size_t)64 * K;

  int l15 = lane & 15;
  int kof = (((lane >> 4) ^ ((l15 >> 1) & 3)) * 8);   // swizzled read slot
  f32x4 acc[4][4] = {};

  // prologue: stage tiles 0 and 1
  gload16(Ab,      &As[0][t*8]);  gload16(Ab2,      &As[0][2048 + t*8]);
  gload16(Bb,      &Bs[0][t*8]);  gload16(Bb2,      &Bs[0][2048 + t*8]);
  gload16(Ab + 32, &As[1][t*8]);  gload16(Ab2 + 32, &As[1][2048 + t*8]);
  gload16(Bb + 32, &Bs[1][t*8]);  gload16(Bb2 + 32, &Bs[1][2048 + t*8]);

  int nsteps = K >> 5;
  int cur = 0;
  for (int tt = 0; tt < nsteps - 1; ++tt){
    asm volatile("s_waitcnt vmcnt(4)" ::: "memory");
    __builtin_amdgcn_s_barrier();
    asm volatile("" ::: "memory");
    s16x8 af[4], bfr[4];
    #pragma unroll
    for (int m = 0; m < 4; m++)
      af[m] = *(const s16x8*)&As[cur][(wrow + m*16 + l15)*32 + kof];
    #pragma unroll
    for (int n = 0; n < 4; n++)
      bfr[n] = *(const s16x8*)&Bs[cur][(wcol + n*16 + l15)*32 + kof];
    __builtin_amdgcn_s_setprio(1);
    #pragma unroll
    for (int m = 0; m < 4; m++){
      #pragma unroll
      for (int n = 0; n < 4; n++){
        acc[m][n] = __builtin_amdgcn_mfma_f32_16x16x32_bf16(af[m], bfr[n], acc[m][n], 0, 0, 0);
      }
    }
    __builtin_amdgcn_s_setprio(0);
    if (tt < nsteps - 2){
      int nb = cur + 2; if (nb >= 3) nb -= 3;
      int kt = (tt + 2) * 32;
      gload16(Ab  + kt, &As[nb][t*8]);  gload16(Ab2 + kt, &As[nb][2048 + t*8]);
      gload16(Bb  + kt, &Bs[nb][t*8]);  gload16(Bb2 + kt, &Bs[nb][2048 + t*8]);
    }
    cur = cur + 1; if (cur >= 3) cur -= 3;
  }
  // final tile: drain all
  asm volatile("s_waitcnt vmcnt(0)" ::: "memory");
  __builtin_amdgcn_s_barrier();
  asm volatile("" ::: "memory");
  {
    s16x8 af[4], bfr[4];
    #pragma unroll
    for (int m = 0; m < 4; m++)
      af[m] = *(const s16x8*)&As[cur][(wrow + m*16 + l15)*32 + kof];
    #pragma unroll
    for (int n = 0; n < 4; n++)
      bfr[n] = *(const s16x8*)&Bs[cur][(wcol + n*16 + l15)*32 + kof];
    #pragma unroll
    for (int m = 0; m < 4; m++){
      #pragma unroll
      for (int n = 0; n < 4; n++){
        acc[m][n] = __builtin_amdgcn_mfma_f32_16x16x32_bf16(af[m], bfr[n], acc[m][n], 0, 0, 0);
      }
    }
  }

  int orow = row0 + wrow + (lane >> 4) * 4;
  int ocol = col0 + wcol + l15;
  #pragma unroll
  for (int m = 0; m < 4; m++){
    #pragma unroll
    for (int n = 0; n < 4; n++){
      #pragma unroll
      for (int i = 0; i < 4; i++){
        Y[(size_t)(orow + m*16 + i) * F_ + ocol + n*16] = acc[m][n][i];
      }
    }
  }
}

// ---------------- kernel 3: fused MFMA delta + GRU gates + output (bucketed) ----------------
// dr = [low_ir|low_rr] @ [lb_ir;lb_rr] ; du = [low_iu|low_ru] @ [lb_iu;lb_ru]
// dic= [low_ic|0] @ [lb_ic;lb_rc]     ; drc= [0|low_rc] @ [lb_ic;lb_rc]
// r=sig(Y0+b_ir+dr), u=sig(Y1+b_iu+du), cand=tanh(Y2+b_ic+dic + r*(Y3+drc))
__global__ __launch_bounds__(256) void delta_final_kernel(
    const float* __restrict__ carry,
    const float* __restrict__ bias_ir, const float* __restrict__ bias_iu,
    const float* __restrict__ bias_ic,
    const float* __restrict__ lb_ir, const float* __restrict__ lb_rr,
    const float* __restrict__ lb_iu, const float* __restrict__ lb_ru,
    const float* __restrict__ lb_ic, const float* __restrict__ lb_rc,
    const int* __restrict__ starts, const int* __restrict__ order,
    const float* __restrict__ low, const float* __restrict__ Yall,
    float* __restrict__ out){
  int s = blockIdx.x;
  int c0 = blockIdx.y * 128;
  __shared__ unsigned short Bsm[3 * 128 * 40];   // 3 stacked [col][k0..31], stride 40
  int t = threadIdx.x;
  const float* lbp[6] = {lb_ir, lb_rr, lb_iu, lb_ru, lb_ic, lb_rc};
  #pragma unroll
  for (int j = 0; j < 6; j++){
    const float* lb = lbp[j] + (size_t)s * R_ * F_;
    unsigned short* Bj = &Bsm[(j >> 1)*5120 + (j & 1)*16];
    #pragma unroll
    for (int it = 0; it < 2; it++){
      int idx = t + it*256;
      int r = idx >> 5, c4 = (idx & 31) * 4;
      float4 v = *(const float4*)&lb[(size_t)r*F_ + c0 + c4];
      Bj[(c4+0)*40 + r] = f2b(v.x);
      Bj[(c4+1)*40 + r] = f2b(v.y);
      Bj[(c4+2)*40 + r] = f2b(v.z);
      Bj[(c4+3)*40 + r] = f2b(v.w);
    }
  }
  __syncthreads();
  int start = starts[s], cnt = starts[s+1] - start;
  if (cnt == 0) return;
  int lane = t & 63, wave = t >> 6;
  int l15 = lane & 15, kq = (lane >> 4) * 8;   // 0,8,16,24
  int ntiles = (cnt + 15) >> 4;
  const float* Y0 = Yall + 0*(size_t)B_*F_;
  const float* Y1 = Yall + 1*(size_t)B_*F_;
  const float* Y2 = Yall + 2*(size_t)B_*F_;
  const float* Y3 = Yall + 3*(size_t)B_*F_;
  int k8 = kq & 15; bool hi = (kq >= 16);
  for (int pt = wave; pt < ntiles*2; pt += 4){
    int mt = pt >> 1, cf0 = (pt & 1) * 4;
    int m = mt*16 + l15; if (m >= cnt) m = cnt - 1;
    int e = order[start + m];
    s16x8 a_r, a_u, a_c1 = {}, a_c2 = {};
    {
      const float* p = &low[((size_t)(hi ? 3 : 0)*B_ + e)*R_ + k8];
      float4 v0 = *(const float4*)p, v1 = *(const float4*)(p+4);
      a_r[0]=f2b(v0.x); a_r[1]=f2b(v0.y); a_r[2]=f2b(v0.z); a_r[3]=f2b(v0.w);
      a_r[4]=f2b(v1.x); a_r[5]=f2b(v1.y); a_r[6]=f2b(v1.z); a_r[7]=f2b(v1.w);
    }
    {
      const float* p = &low[((size_t)(hi ? 4 : 1)*B_ + e)*R_ + k8];
      float4 v0 = *(const float4*)p, v1 = *(const float4*)(p+4);
      a_u[0]=f2b(v0.x); a_u[1]=f2b(v0.y); a_u[2]=f2b(v0.z); a_u[3]=f2b(v0.w);
      a_u[4]=f2b(v1.x); a_u[5]=f2b(v1.y); a_u[6]=f2b(v1.z); a_u[7]=f2b(v1.w);
    }
    if (!hi){
      const float* p = &low[((size_t)2*B_ + e)*R_ + k8];
      float4 v0 = *(const float4*)p, v1 = *(const float4*)(p+4);
      a_c1[0]=f2b(v0.x); a_c1[1]=f2b(v0.y); a_c1[2]=f2b(v0.z); a_c1[3]=f2b(v0.w);
      a_c1[4]=f2b(v1.x); a_c1[5]=f2b(v1.y); a_c1[6]=f2b(v1.z); a_c1[7]=f2b(v1.w);
    } else {
      const float* p = &low[((size_t)5*B_ + e)*R_ + k8];
      float4 v0 = *(const float4*)p, v1 = *(const float4*)(p+4);
      a_c2[0]=f2b(v0.x); a_c2[1]=f2b(v0.y); a_c2[2]=f2b(v0.z); a_c2[3]=f2b(v0.w);
      a_c2[4]=f2b(v1.x); a_c2[5]=f2b(v1.y); a_c2[6]=f2b(v1.z); a_c2[7]=f2b(v1.w);
    }
    int rowb = (lane >> 4) * 4;
    int erow[4]; bool wok[4];
    #pragma unroll
    for (int i = 0; i < 4; i++){
      int mm = mt*16 + rowb + i;
      wok[i] = (mm < cnt);
      erow[i] = order[start + (wok[i] ? mm : cnt - 1)];
    }
    #pragma unroll
    for (int cf = cf0; cf < cf0 + 4; cf++){
      int col = cf*16 + l15;
      s16x8 b_r = *(const s16x8*)&Bsm[0*5120 + col*40 + kq];
      s16x8 b_u = *(const s16x8*)&Bsm[1*5120 + col*40 + kq];
      s16x8 b_c = *(const s16x8*)&Bsm[2*5120 + col*40 + kq];
      f32x4 zero = {};
      f32x4 dr  = __builtin_amdgcn_mfma_f32_16x16x32_bf16(a_r,  b_r, zero, 0, 0, 0);
      f32x4 du  = __builtin_amdgcn_mfma_f32_16x16x32_bf16(a_u,  b_u, zero, 0, 0, 0);
      f32x4 dic = __builtin_amdgcn_mfma_f32_16x16x32_bf16(a_c1, b_c, zero, 0, 0, 0);
      f32x4 drc = __builtin_amdgcn_mfma_f32_16x16x32_bf16(a_c2, b_c, zero, 0, 0, 0);
      int oc = c0 + col;
      float br = bias_ir[oc], bu = bias_iu[oc], bc = bias_ic[oc];
      #pragma unroll
      for (int i = 0; i < 4; i++){
        if (wok[i]){
          size_t idx = (size_t)erow[i]*F_ + oc;
          float zr  = Y0[idx] + br + dr[i];
          float zu  = Y1[idx] + bu + du[i];
          float zic = Y2[idx] + bc + dic[i];
          float zrc = Y3[idx] + drc[i];
          float cv  = carry[idx];
          float rr = 1.f/(1.f+__expf(-zr));
          float uu = 1.f/(1.f+__expf(-zu));
          float a = zic + rr*zrc;
          float ee = __expf(-2.f*fabsf(a));
          float cand = copysignf((1.f-ee)/(1.f+ee), a);
          out[idx] = (1.f-uu)*cand + uu*cv;
        }
      }
    }
  }
}

extern "C" void kernel_launch(void* const* d_in, const int* in_sizes, int n_in,
                              void* d_out, int out_size, void* d_ws, size_t ws_size,
                              hipStream_t stream){
  const float* carry   = (const float*)d_in[0];
  const float* x       = (const float*)d_in[1];
  const int*   ids     = (const int*)d_in[2];
  const float* w_ir    = (const float*)d_in[3];
  const float* bias_ir = (const float*)d_in[4];
  const float* la_ir   = (const float*)d_in[5];
  const float* lb_ir   = (const float*)d_in[6];
  const float* w_iu    = (const float*)d_in[7];
  const float* bias_iu = (const float*)d_in[8];
  const float* la_iu   = (const float*)d_in[9];
  const float* lb_iu   = (const float*)d_in[10];
  const float* w_ic    = (const float*)d_in[11];
  const float* bias_ic = (const float*)d_in[12];
  const float* la_ic   = (const float*)d_in[13];
  const float* lb_ic   = (const float*)d_in[14];
  const float* w_rr    = (const float*)d_in[15];
  const float* la_rr   = (const float*)d_in[16];
  const float* lb_rr   = (const float*)d_in[17];
  const float* w_ru    = (const float*)d_in[18];
  const float* la_ru   = (const float*)d_in[19];
  const float* lb_ru   = (const float*)d_in[20];
  const float* w_rc    = (const float*)d_in[21];
  const float* la_rc   = (const float*)d_in[22];
  const float* lb_rc   = (const float*)d_in[23];

  char* ws = (char*)d_ws;
  unsigned short* XC     = (unsigned short*)(ws + 0);          // 8 MiB
  unsigned short* Wt_all = (unsigned short*)(ws + 8388608);    // 12 MiB
  float* Yall = (float*)(ws + 20971520);                       // 32 MiB (4 x 8 MiB)
  float* low  = (float*)(ws + 54525952);                       // 768 KiB
  int* starts = (int*)(ws + 55312384);
  int* order  = (int*)(ws + 55313408);

  prep_kernel<<<dim3(3585), dim3(256), 0, stream>>>(x, carry, XC,
                                                    w_ir, w_rr, w_iu, w_ru, w_ic, w_rc,
                                                    Wt_all, ids, starts, order);
  gemm_low_kernel<<<dim3(896), dim3(256), 0, stream>>>(XC, Wt_all, Yall,
                                                       la_ir, la_iu, la_ic,
                                                       la_rr, la_ru, la_rc,
                                                       starts, order, low);
  delta_final_kernel<<<dim3(64, 8), dim3(256), 0, stream>>>(carry, bias_ir, bias_iu, bias_ic,
                                                            lb_ir, lb_rr, lb_iu, lb_ru,
                                                            lb_ic, lb_rc,
                                                            starts, order, low, Yall,
                                                            (float*)d_out);
}

// Round 8
// 90.281 us; speedup vs baseline: 1.4391x; 1.0069x over previous
//
#include <hip/hip_runtime.h>
#include <stdint.h>

#define B_  2048
#define D_  1024
#define F_  1024
#define S_  64
#define R_  16

typedef __attribute__((ext_vector_type(8))) short  s16x8;
typedef __attribute__((ext_vector_type(4))) unsigned short u16x4;
typedef __attribute__((ext_vector_type(8))) unsigned short u16x8;
typedef __attribute__((ext_vector_type(4))) float  f32x4;

__device__ __forceinline__ unsigned short f2b(float f){
  unsigned u = __float_as_uint(f);
  u = u + 0x7fffu + ((u >> 16) & 1u);   // RNE to bf16
  return (unsigned short)(u >> 16);
}
__device__ __forceinline__ float b2f(unsigned short s){
  return __uint_as_float(((unsigned)s) << 16);
}

__device__ __forceinline__ void gload16(const void* g, void* l){
  __builtin_amdgcn_global_load_lds((const __attribute__((address_space(1))) unsigned int*)g,
                                   (__attribute__((address_space(3))) unsigned int*)l, 16, 0, 0);
}

// Wt_all element offsets: W0t(ir+rr,K2048)=0, W1t(iu+ru,K2048)=2M, W2t(ic,K1024)=4M, W3t(rc)=5M
#define W0OFF 0
#define W1OFF 2097152
#define W2OFF 4194304
#define W3OFF 5242880

// ---------------- kernel 1: fused prep = cast_xc | wcast | bucket (block-partitioned) -----
__global__ __launch_bounds__(256) void prep_kernel(
    const float* __restrict__ x, const float* __restrict__ carry,
    unsigned short* __restrict__ XC,
    const float* __restrict__ w_ir, const float* __restrict__ w_rr,
    const float* __restrict__ w_iu, const float* __restrict__ w_ru,
    const float* __restrict__ w_ic, const float* __restrict__ w_rc,
    unsigned short* __restrict__ Wt_all,
    const int* __restrict__ ids, int* __restrict__ starts, int* __restrict__ order){
  int bx = blockIdx.x;
  int t = threadIdx.x;
  if (bx < 2048){
    int i = bx * 256 + t;
    int b = i >> 8;
    int j = (i & 255) * 4;
    float4 xv = *(const float4*)&x[(size_t)b*D_ + j];
    float4 cv = *(const float4*)&carry[(size_t)b*F_ + j];
    u16x4 xs, cs;
    xs[0]=f2b(xv.x); xs[1]=f2b(xv.y); xs[2]=f2b(xv.z); xs[3]=f2b(xv.w);
    cs[0]=f2b(cv.x); cs[1]=f2b(cv.y); cs[2]=f2b(cv.z); cs[3]=f2b(cv.w);
    *(u16x4*)&XC[(size_t)b*2048 + j]        = xs;
    *(u16x4*)&XC[(size_t)b*2048 + 1024 + j] = cs;
    return;
  }
  if (bx < 3584){
    int wb = bx - 2048;
    int g = wb >> 8, xb = wb & 255;
    const float* W; unsigned short* O; int st, ko;
    switch(g){
      case 0:  W=w_ir; O=Wt_all+W0OFF; st=2048; ko=0;    break;
      case 1:  W=w_rr; O=Wt_all+W0OFF; st=2048; ko=1024; break;
      case 2:  W=w_iu; O=Wt_all+W1OFF; st=2048; ko=0;    break;
      case 3:  W=w_ru; O=Wt_all+W1OFF; st=2048; ko=1024; break;
      case 4:  W=w_ic; O=Wt_all+W2OFF; st=1024; ko=0;    break;
      default: W=w_rc; O=Wt_all+W3OFF; st=1024; ko=0;    break;
    }
    __shared__ unsigned short T[64][72];   // row stride 144B (9*16B)
    int n0 = (xb & 15) * 64;
    int k0 = (xb >> 4) * 64;
    int c4 = (t & 15) * 4;
    int kk = t >> 4;
    #pragma unroll
    for (int i = 0; i < 4; i++){
      int k = kk + i*16;
      float4 v = *(const float4*)&W[(size_t)(k0+k)*F_ + n0 + c4];
      T[c4+0][k] = f2b(v.x); T[c4+1][k] = f2b(v.y); T[c4+2][k] = f2b(v.z); T[c4+3][k] = f2b(v.w);
    }
    __syncthreads();
    int n = t >> 2, ch = (t & 3) * 16;
    u16x8 a = *(const u16x8*)&T[n][ch];
    u16x8 b = *(const u16x8*)&T[n][ch+8];
    *(u16x8*)&O[(size_t)(n0+n)*st + ko + k0 + ch]     = a;
    *(u16x8*)&O[(size_t)(n0+n)*st + ko + k0 + ch + 8] = b;
    return;
  }
  // bucket
  __shared__ int cnt[S_]; __shared__ int off[S_+1]; __shared__ int cur[S_];
  if (t < S_) cnt[t] = 0;
  __syncthreads();
  for (int b = t; b < B_; b += 256) atomicAdd(&cnt[ids[b]], 1);
  __syncthreads();
  if (t == 0){ off[0] = 0; for (int s2 = 0; s2 < S_; s2++) off[s2+1] = off[s2] + cnt[s2]; }
  __syncthreads();
  if (t < S_) cur[t] = off[t];
  __syncthreads();
  for (int b = t; b < B_; b += 256){ int p = atomicAdd(&cur[ids[b]], 1); order[p] = b; }
  if (t < S_+1) starts[t] = off[t];
}

// ---------------- kernel 2: GEMM (blocks 0..255) + low (blocks 256..639) ------------------
// gemm: BM=256 x BN=128 tile, 4 waves of 128x64 (8m x 4n), 2-buffer LDS, k-slot swizzle,
//       Y written bf16.  u0: K2048 ir+rr, u1: K2048 iu+ru, u2: K1024 ic(x), u3: K1024 rc(c).
__global__ __launch_bounds__(256, 2) void gemm_low_kernel(
    const unsigned short* __restrict__ XC,
    const unsigned short* __restrict__ Wt_all,
    unsigned short* __restrict__ Yall,
    const float* __restrict__ la_ir, const float* __restrict__ la_iu,
    const float* __restrict__ la_ic, const float* __restrict__ la_rr,
    const float* __restrict__ la_ru, const float* __restrict__ la_rc,
    const int* __restrict__ starts, const int* __restrict__ order,
    float* __restrict__ low){
  __shared__ __align__(16) unsigned short smem[24576];   // 48 KB overlay
  int t = threadIdx.x;
  int bx = blockIdx.x;

  if (bx >= 256){
    // ---- low path ----
    int lb = bx - 256;
    int s = lb & 63, g = lb >> 6;
    const float* la;
    switch(g){ case 0: la=la_ir; break; case 1: la=la_iu; break; case 2: la=la_ic; break;
               case 3: la=la_rr; break; case 4: la=la_ru; break; default: la=la_rc; break; }
    int kofs = (g < 3) ? 0 : 1024;
    la += (size_t)s * D_ * R_;
    unsigned short* LA = smem;             // [r][d] 16 x 1032 (pad 8)
    for (int i4 = t; i4 < D_*R_/4; i4 += 256){
      float4 v = *(const float4*)&la[i4*4];
      int d = i4 >> 2, r0 = (i4 & 3) * 4;
      LA[(r0+0)*1032 + d] = f2b(v.x);
      LA[(r0+1)*1032 + d] = f2b(v.y);
      LA[(r0+2)*1032 + d] = f2b(v.z);
      LA[(r0+3)*1032 + d] = f2b(v.w);
    }
    __syncthreads();
    int start = starts[s], cnt = starts[s+1] - start;
    if (cnt == 0) return;
    int lane = t & 63, wave = t >> 6;
    int l15 = lane & 15, kq = (lane >> 4) * 8;
    int ntiles = (cnt + 15) >> 4;
    for (int mt = wave*2; mt < ntiles; mt += 8){
      bool two = (mt + 1 < ntiles);
      int m0 = mt*16 + l15;       if (m0 >= cnt) m0 = cnt - 1;
      int m1 = (mt+1)*16 + l15;   if (m1 >= cnt) m1 = cnt - 1;
      int e0 = order[start + m0];
      int e1 = two ? order[start + m1] : e0;
      const unsigned short* A0 = XC + (size_t)e0*2048 + kofs + kq;
      const unsigned short* A1 = XC + (size_t)e1*2048 + kofs + kq;
      const unsigned short* Bp = &LA[l15*1032 + kq];
      f32x4 acc0 = {}, acc1 = {};
      #pragma unroll 4
      for (int kt = 0; kt < 1024; kt += 32){
        s16x8 a0 = *(const s16x8*)(A0 + kt);
        s16x8 a1 = *(const s16x8*)(A1 + kt);
        s16x8 b  = *(const s16x8*)(Bp + kt);
        acc0 = __builtin_amdgcn_mfma_f32_16x16x32_bf16(a0, b, acc0, 0, 0, 0);
        acc1 = __builtin_amdgcn_mfma_f32_16x16x32_bf16(a1, b, acc1, 0, 0, 0);
      }
      int rowb = (lane >> 4) * 4;
      #pragma unroll
      for (int i = 0; i < 4; i++){
        int m = mt*16 + rowb + i;
        if (m < cnt){
          int e = order[start + m];
          low[((size_t)g*B_ + e)*R_ + l15] = acc0[i];
        }
      }
      if (two){
        #pragma unroll
        for (int i = 0; i < 4; i++){
          int m = (mt+1)*16 + rowb + i;
          if (m < cnt){
            int e = order[start + m];
            low[((size_t)g*B_ + e)*R_ + l15] = acc1[i];
          }
        }
      }
    }
    return;
  }

  // ---- gemm path ----
  int u = bx >> 6;                  // 64 blocks/unit
  int tile = bx & 63;
  int K = (u < 2) ? 2048 : 1024;
  int kofs = (u == 3) ? 1024 : 0;
  const size_t uoffs[4] = {W0OFF, W1OFF, W2OFF, W3OFF};
  const unsigned short* Wt = Wt_all + uoffs[u];
  unsigned short* Y = Yall + (size_t)u * ((size_t)B_ * F_);

  unsigned short (*As)[8192] = (unsigned short(*)[8192])smem;            // [2][256*32]
  unsigned short (*Bs)[4096] = (unsigned short(*)[4096])(smem + 16384);  // [2][128*32]

  int lane = t & 63, wave = t >> 6;
  int mt = tile >> 3, nt = tile & 7;       // 8 m-tiles x 8 n-tiles
  int row0 = mt * 256, col0 = nt * 128;
  int wrow = (wave >> 1) * 128, wcol = (wave & 1) * 64;

  int arow = t >> 2;                           // 0..63
  int achk = ((t & 3) ^ ((t >> 3) & 3)) * 8;   // swizzled source k-slot

  const unsigned short* Ab = XC + (size_t)(row0 + arow) * 2048 + kofs + achk;
  const unsigned short* Bb = Wt + (size_t)(col0 + arow) * K + achk;

  int l15 = lane & 15;
  int kof = (((lane >> 4) ^ ((l15 >> 1) & 3)) * 8);   // swizzled read slot
  f32x4 acc[8][4] = {};

#define STAGE_T(bf, kt) \
  gload16(Ab + (kt),                       &As[bf][t*8]);        \
  gload16(Ab + (size_t)64*2048 + (kt),     &As[bf][2048 + t*8]); \
  gload16(Ab + (size_t)128*2048 + (kt),    &As[bf][4096 + t*8]); \
  gload16(Ab + (size_t)192*2048 + (kt),    &As[bf][6144 + t*8]); \
  gload16(Bb + (kt),                       &Bs[bf][t*8]);        \
  gload16(Bb + (size_t)64*K + (kt),        &Bs[bf][2048 + t*8]);

  STAGE_T(0, 0);
  __syncthreads();

  int nsteps = K >> 5;
  int cur = 0;
  for (int tt = 0; tt < nsteps - 1; ++tt){
    int nxt = cur ^ 1;
    STAGE_T(nxt, (tt + 1) * 32);
    s16x8 af[8], bfr[4];
    #pragma unroll
    for (int m = 0; m < 8; m++)
      af[m] = *(const s16x8*)&As[cur][(wrow + m*16 + l15)*32 + kof];
    #pragma unroll
    for (int n = 0; n < 4; n++)
      bfr[n] = *(const s16x8*)&Bs[cur][(wcol + n*16 + l15)*32 + kof];
    __builtin_amdgcn_s_setprio(1);
    #pragma unroll
    for (int m = 0; m < 8; m++){
      #pragma unroll
      for (int n = 0; n < 4; n++){
        acc[m][n] = __builtin_amdgcn_mfma_f32_16x16x32_bf16(af[m], bfr[n], acc[m][n], 0, 0, 0);
      }
    }
    __builtin_amdgcn_s_setprio(0);
    __syncthreads();
    cur = nxt;
  }
  {
    s16x8 af[8], bfr[4];
    #pragma unroll
    for (int m = 0; m < 8; m++)
      af[m] = *(const s16x8*)&As[cur][(wrow + m*16 + l15)*32 + kof];
    #pragma unroll
    for (int n = 0; n < 4; n++)
      bfr[n] = *(const s16x8*)&Bs[cur][(wcol + n*16 + l15)*32 + kof];
    #pragma unroll
    for (int m = 0; m < 8; m++){
      #pragma unroll
      for (int n = 0; n < 4; n++){
        acc[m][n] = __builtin_amdgcn_mfma_f32_16x16x32_bf16(af[m], bfr[n], acc[m][n], 0, 0, 0);
      }
    }
  }
#undef STAGE_T

  int orow = row0 + wrow + (lane >> 4) * 4;
  int ocol = col0 + wcol + l15;
  #pragma unroll
  for (int m = 0; m < 8; m++){
    #pragma unroll
    for (int n = 0; n < 4; n++){
      #pragma unroll
      for (int i = 0; i < 4; i++){
        Y[(size_t)(orow + m*16 + i) * F_ + ocol + n*16] = f2b(acc[m][n][i]);
      }
    }
  }
}

// ---------------- kernel 3: fused MFMA delta + GRU gates + output (bucketed, bf16 Y) ------
__global__ __launch_bounds__(256) void delta_final_kernel(
    const float* __restrict__ carry,
    const float* __restrict__ bias_ir, const float* __restrict__ bias_iu,
    const float* __restrict__ bias_ic,
    const float* __restrict__ lb_ir, const float* __restrict__ lb_rr,
    const float* __restrict__ lb_iu, const float* __restrict__ lb_ru,
    const float* __restrict__ lb_ic, const float* __restrict__ lb_rc,
    const int* __restrict__ starts, const int* __restrict__ order,
    const float* __restrict__ low, const unsigned short* __restrict__ Yall,
    float* __restrict__ out){
  int s = blockIdx.x;
  int c0 = blockIdx.y * 128;
  __shared__ unsigned short Bsm[3 * 128 * 40];   // 3 stacked [col][k0..31], stride 40
  int t = threadIdx.x;
  const float* lbp[6] = {lb_ir, lb_rr, lb_iu, lb_ru, lb_ic, lb_rc};
  #pragma unroll
  for (int j = 0; j < 6; j++){
    const float* lb = lbp[j] + (size_t)s * R_ * F_;
    unsigned short* Bj = &Bsm[(j >> 1)*5120 + (j & 1)*16];
    #pragma unroll
    for (int it = 0; it < 2; it++){
      int idx = t + it*256;
      int r = idx >> 5, c4 = (idx & 31) * 4;
      float4 v = *(const float4*)&lb[(size_t)r*F_ + c0 + c4];
      Bj[(c4+0)*40 + r] = f2b(v.x);
      Bj[(c4+1)*40 + r] = f2b(v.y);
      Bj[(c4+2)*40 + r] = f2b(v.z);
      Bj[(c4+3)*40 + r] = f2b(v.w);
    }
  }
  __syncthreads();
  int start = starts[s], cnt = starts[s+1] - start;
  if (cnt == 0) return;
  int lane = t & 63, wave = t >> 6;
  int l15 = lane & 15, kq = (lane >> 4) * 8;   // 0,8,16,24
  int ntiles = (cnt + 15) >> 4;
  const unsigned short* Y0 = Yall + 0*(size_t)B_*F_;
  const unsigned short* Y1 = Yall + 1*(size_t)B_*F_;
  const unsigned short* Y2 = Yall + 2*(size_t)B_*F_;
  const unsigned short* Y3 = Yall + 3*(size_t)B_*F_;
  int k8 = kq & 15; bool hi = (kq >= 16);
  for (int pt = wave; pt < ntiles*2; pt += 4){
    int mt = pt >> 1, cf0 = (pt & 1) * 4;
    int m = mt*16 + l15; if (m >= cnt) m = cnt - 1;
    int e = order[start + m];
    s16x8 a_r, a_u, a_c1 = {}, a_c2 = {};
    {
      const float* p = &low[((size_t)(hi ? 3 : 0)*B_ + e)*R_ + k8];
      float4 v0 = *(const float4*)p, v1 = *(const float4*)(p+4);
      a_r[0]=f2b(v0.x); a_r[1]=f2b(v0.y); a_r[2]=f2b(v0.z); a_r[3]=f2b(v0.w);
      a_r[4]=f2b(v1.x); a_r[5]=f2b(v1.y); a_r[6]=f2b(v1.z); a_r[7]=f2b(v1.w);
    }
    {
      const float* p = &low[((size_t)(hi ? 4 : 1)*B_ + e)*R_ + k8];
      float4 v0 = *(const float4*)p, v1 = *(const float4*)(p+4);
      a_u[0]=f2b(v0.x); a_u[1]=f2b(v0.y); a_u[2]=f2b(v0.z); a_u[3]=f2b(v0.w);
      a_u[4]=f2b(v1.x); a_u[5]=f2b(v1.y); a_u[6]=f2b(v1.z); a_u[7]=f2b(v1.w);
    }
    if (!hi){
      const float* p = &low[((size_t)2*B_ + e)*R_ + k8];
      float4 v0 = *(const float4*)p, v1 = *(const float4*)(p+4);
      a_c1[0]=f2b(v0.x); a_c1[1]=f2b(v0.y); a_c1[2]=f2b(v0.z); a_c1[3]=f2b(v0.w);
      a_c1[4]=f2b(v1.x); a_c1[5]=f2b(v1.y); a_c1[6]=f2b(v1.z); a_c1[7]=f2b(v1.w);
    } else {
      const float* p = &low[((size_t)5*B_ + e)*R_ + k8];
      float4 v0 = *(const float4*)p, v1 = *(const float4*)(p+4);
      a_c2[0]=f2b(v0.x); a_c2[1]=f2b(v0.y); a_c2[2]=f2b(v0.z); a_c2[3]=f2b(v0.w);
      a_c2[4]=f2b(v1.x); a_c2[5]=f2b(v1.y); a_c2[6]=f2b(v1.z); a_c2[7]=f2b(v1.w);
    }
    int rowb = (lane >> 4) * 4;
    int erow[4]; bool wok[4];
    #pragma unroll
    for (int i = 0; i < 4; i++){
      int mm = mt*16 + rowb + i;
      wok[i] = (mm < cnt);
      erow[i] = order[start + (wok[i] ? mm : cnt - 1)];
    }
    #pragma unroll
    for (int cf = cf0; cf < cf0 + 4; cf++){
      int col = cf*16 + l15;
      s16x8 b_r = *(const s16x8*)&Bsm[0*5120 + col*40 + kq];
      s16x8 b_u = *(const s16x8*)&Bsm[1*5120 + col*40 + kq];
      s16x8 b_c = *(const s16x8*)&Bsm[2*5120 + col*40 + kq];
      f32x4 zero = {};
      f32x4 dr  = __builtin_amdgcn_mfma_f32_16x16x32_bf16(a_r,  b_r, zero, 0, 0, 0);
      f32x4 du  = __builtin_amdgcn_mfma_f32_16x16x32_bf16(a_u,  b_u, zero, 0, 0, 0);
      f32x4 dic = __builtin_amdgcn_mfma_f32_16x16x32_bf16(a_c1, b_c, zero, 0, 0, 0);
      f32x4 drc = __builtin_amdgcn_mfma_f32_16x16x32_bf16(a_c2, b_c, zero, 0, 0, 0);
      int oc = c0 + col;
      float br = bias_ir[oc], bu = bias_iu[oc], bc = bias_ic[oc];
      #pragma unroll
      for (int i = 0; i < 4; i++){
        if (wok[i]){
          size_t idx = (size_t)erow[i]*F_ + oc;
          float zr  = b2f(Y0[idx]) + br + dr[i];
          float zu  = b2f(Y1[idx]) + bu + du[i];
          float zic = b2f(Y2[idx]) + bc + dic[i];
          float zrc = b2f(Y3[idx]) + drc[i];
          float cv  = carry[idx];
          float rr = 1.f/(1.f+__expf(-zr));
          float uu = 1.f/(1.f+__expf(-zu));
          float a = zic + rr*zrc;
          float ee = __expf(-2.f*fabsf(a));
          float cand = copysignf((1.f-ee)/(1.f+ee), a);
          out[idx] = (1.f-uu)*cand + uu*cv;
        }
      }
    }
  }
}

extern "C" void kernel_launch(void* const* d_in, const int* in_sizes, int n_in,
                              void* d_out, int out_size, void* d_ws, size_t ws_size,
                              hipStream_t stream){
  const float* carry   = (const float*)d_in[0];
  const float* x       = (const float*)d_in[1];
  const int*   ids     = (const int*)d_in[2];
  const float* w_ir    = (const float*)d_in[3];
  const float* bias_ir = (const float*)d_in[4];
  const float* la_ir   = (const float*)d_in[5];
  const float* lb_ir   = (const float*)d_in[6];
  const float* w_iu    = (const float*)d_in[7];
  const float* bias_iu = (const float*)d_in[8];
  const float* la_iu   = (const float*)d_in[9];
  const float* lb_iu   = (const float*)d_in[10];
  const float* w_ic    = (const float*)d_in[11];
  const float* bias_ic = (const float*)d_in[12];
  const float* la_ic   = (const float*)d_in[13];
  const float* lb_ic   = (const float*)d_in[14];
  const float* w_rr    = (const float*)d_in[15];
  const float* la_rr   = (const float*)d_in[16];
  const float* lb_rr   = (const float*)d_in[17];
  const float* w_ru    = (const float*)d_in[18];
  const float* la_ru   = (const float*)d_in[19];
  const float* lb_ru   = (const float*)d_in[20];
  const float* w_rc    = (const float*)d_in[21];
  const float* la_rc   = (const float*)d_in[22];
  const float* lb_rc   = (const float*)d_in[23];

  char* ws = (char*)d_ws;
  unsigned short* XC     = (unsigned short*)(ws + 0);          // 8 MiB
  unsigned short* Wt_all = (unsigned short*)(ws + 8388608);    // 12 MiB
  unsigned short* Yall   = (unsigned short*)(ws + 20971520);   // 16 MiB (4 x 4 MiB bf16)
  float* low  = (float*)(ws + 37748736);                       // 768 KiB
  int* starts = (int*)(ws + 38535168);
  int* order  = (int*)(ws + 38536192);

  prep_kernel<<<dim3(3585), dim3(256), 0, stream>>>(x, carry, XC,
                                                    w_ir, w_rr, w_iu, w_ru, w_ic, w_rc,
                                                    Wt_all, ids, starts, order);
  gemm_low_kernel<<<dim3(640), dim3(256), 0, stream>>>(XC, Wt_all, Yall,
                                                       la_ir, la_iu, la_ic,
                                                       la_rr, la_ru, la_rc,
                                                       starts, order, low);
  delta_final_kernel<<<dim3(64, 8), dim3(256), 0, stream>>>(carry, bias_ir, bias_iu, bias_ic,
                                                            lb_ir, lb_rr, lb_iu, lb_ru,
                                                            lb_ic, lb_rc,
                                                            starts, order, low, Yall,
                                                            (float*)d_out);
}

// Round 9
// 83.279 us; speedup vs baseline: 1.5601x; 1.0841x over previous
//
#include <hip/hip_runtime.h>
#include <stdint.h>

#define B_  2048
#define D_  1024
#define F_  1024
#define S_  64
#define R_  16

typedef __attribute__((ext_vector_type(8))) short  s16x8;
typedef __attribute__((ext_vector_type(4))) unsigned short u16x4;
typedef __attribute__((ext_vector_type(8))) unsigned short u16x8;
typedef __attribute__((ext_vector_type(4))) float  f32x4;

__device__ __forceinline__ unsigned short f2b(float f){
  unsigned u = __float_as_uint(f);
  u = u + 0x7fffu + ((u >> 16) & 1u);   // RNE to bf16
  return (unsigned short)(u >> 16);
}
__device__ __forceinline__ float b2f(unsigned short s){
  return __uint_as_float(((unsigned)s) << 16);
}

__device__ __forceinline__ void gload16(const void* g, void* l){
  __builtin_amdgcn_global_load_lds((const __attribute__((address_space(1))) unsigned int*)g,
                                   (__attribute__((address_space(3))) unsigned int*)l, 16, 0, 0);
}

// Wt_all element offsets: W0t(ir+rr,K2048)=0, W1t(iu+ru,K2048)=2M, W2t(ic,K1024)=4M, W3t(rc)=5M
#define W0OFF 0
#define W1OFF 2097152
#define W2OFF 4194304
#define W3OFF 5242880

// ---------------- kernel 1: fused prep = cast_xc | wcast | bucket (block-partitioned) -----
__global__ __launch_bounds__(256) void prep_kernel(
    const float* __restrict__ x, const float* __restrict__ carry,
    unsigned short* __restrict__ XC,
    const float* __restrict__ w_ir, const float* __restrict__ w_rr,
    const float* __restrict__ w_iu, const float* __restrict__ w_ru,
    const float* __restrict__ w_ic, const float* __restrict__ w_rc,
    unsigned short* __restrict__ Wt_all,
    const int* __restrict__ ids, int* __restrict__ starts, int* __restrict__ order){
  int bx = blockIdx.x;
  int t = threadIdx.x;
  if (bx < 2048){
    int i = bx * 256 + t;
    int b = i >> 8;
    int j = (i & 255) * 4;
    float4 xv = *(const float4*)&x[(size_t)b*D_ + j];
    float4 cv = *(const float4*)&carry[(size_t)b*F_ + j];
    u16x4 xs, cs;
    xs[0]=f2b(xv.x); xs[1]=f2b(xv.y); xs[2]=f2b(xv.z); xs[3]=f2b(xv.w);
    cs[0]=f2b(cv.x); cs[1]=f2b(cv.y); cs[2]=f2b(cv.z); cs[3]=f2b(cv.w);
    *(u16x4*)&XC[(size_t)b*2048 + j]        = xs;
    *(u16x4*)&XC[(size_t)b*2048 + 1024 + j] = cs;
    return;
  }
  if (bx < 3584){
    int wb = bx - 2048;
    int g = wb >> 8, xb = wb & 255;
    const float* W; unsigned short* O; int st, ko;
    switch(g){
      case 0:  W=w_ir; O=Wt_all+W0OFF; st=2048; ko=0;    break;
      case 1:  W=w_rr; O=Wt_all+W0OFF; st=2048; ko=1024; break;
      case 2:  W=w_iu; O=Wt_all+W1OFF; st=2048; ko=0;    break;
      case 3:  W=w_ru; O=Wt_all+W1OFF; st=2048; ko=1024; break;
      case 4:  W=w_ic; O=Wt_all+W2OFF; st=1024; ko=0;    break;
      default: W=w_rc; O=Wt_all+W3OFF; st=1024; ko=0;    break;
    }
    __shared__ unsigned short T[64][72];   // row stride 144B (9*16B)
    int n0 = (xb & 15) * 64;
    int k0 = (xb >> 4) * 64;
    int c4 = (t & 15) * 4;
    int kk = t >> 4;
    #pragma unroll
    for (int i = 0; i < 4; i++){
      int k = kk + i*16;
      float4 v = *(const float4*)&W[(size_t)(k0+k)*F_ + n0 + c4];
      T[c4+0][k] = f2b(v.x); T[c4+1][k] = f2b(v.y); T[c4+2][k] = f2b(v.z); T[c4+3][k] = f2b(v.w);
    }
    __syncthreads();
    int n = t >> 2, ch = (t & 3) * 16;
    u16x8 a = *(const u16x8*)&T[n][ch];
    u16x8 b = *(const u16x8*)&T[n][ch+8];
    *(u16x8*)&O[(size_t)(n0+n)*st + ko + k0 + ch]     = a;
    *(u16x8*)&O[(size_t)(n0+n)*st + ko + k0 + ch + 8] = b;
    return;
  }
  // bucket
  __shared__ int cnt[S_]; __shared__ int off[S_+1]; __shared__ int cur[S_];
  if (t < S_) cnt[t] = 0;
  __syncthreads();
  for (int b = t; b < B_; b += 256) atomicAdd(&cnt[ids[b]], 1);
  __syncthreads();
  if (t == 0){ off[0] = 0; for (int s2 = 0; s2 < S_; s2++) off[s2+1] = off[s2] + cnt[s2]; }
  __syncthreads();
  if (t < S_) cur[t] = off[t];
  __syncthreads();
  for (int b = t; b < B_; b += 256){ int p = atomicAdd(&cur[ids[b]], 1); order[p] = b; }
  if (t < S_+1) starts[t] = off[t];
}

// ---------------- kernel 2: GEMM (blocks 0..511, 128x128 tiles) + low (512..895) ----------
// gemm: r4-winning shape — 128^2 tile, 4 waves of 64x64, 2-phase plain __syncthreads,
//       32 KB gemm LDS, k-slot swizzle, bf16 Y. Units: u0/u1 K=2048 first, u2/u3 K=1024.
// Total smem 33 KB (low's LA) -> 4 blocks/CU; __launch_bounds__(256,4).
__global__ __launch_bounds__(256, 4) void gemm_low_kernel(
    const unsigned short* __restrict__ XC,
    const unsigned short* __restrict__ Wt_all,
    unsigned short* __restrict__ Yall,
    const float* __restrict__ la_ir, const float* __restrict__ la_iu,
    const float* __restrict__ la_ic, const float* __restrict__ la_rr,
    const float* __restrict__ la_ru, const float* __restrict__ la_rc,
    const int* __restrict__ starts, const int* __restrict__ order,
    float* __restrict__ low){
  __shared__ __align__(16) unsigned short smem[16512];   // 33 KB overlay (low LA is max)
  int t = threadIdx.x;
  int bx = blockIdx.x;

  if (bx >= 512){
    // ---- low path ----
    int lb = bx - 512;
    int s = lb & 63, g = lb >> 6;
    const float* la;
    switch(g){ case 0: la=la_ir; break; case 1: la=la_iu; break; case 2: la=la_ic; break;
               case 3: la=la_rr; break; case 4: la=la_ru; break; default: la=la_rc; break; }
    int kofs = (g < 3) ? 0 : 1024;
    la += (size_t)s * D_ * R_;
    unsigned short* LA = smem;             // [r][d] 16 x 1032 (pad 8)
    for (int i4 = t; i4 < D_*R_/4; i4 += 256){
      float4 v = *(const float4*)&la[i4*4];
      int d = i4 >> 2, r0 = (i4 & 3) * 4;
      LA[(r0+0)*1032 + d] = f2b(v.x);
      LA[(r0+1)*1032 + d] = f2b(v.y);
      LA[(r0+2)*1032 + d] = f2b(v.z);
      LA[(r0+3)*1032 + d] = f2b(v.w);
    }
    __syncthreads();
    int start = starts[s], cnt = starts[s+1] - start;
    if (cnt == 0) return;
    int lane = t & 63, wave = t >> 6;
    int l15 = lane & 15, kq = (lane >> 4) * 8;
    int ntiles = (cnt + 15) >> 4;
    for (int mt = wave*2; mt < ntiles; mt += 8){
      bool two = (mt + 1 < ntiles);
      int m0 = mt*16 + l15;       if (m0 >= cnt) m0 = cnt - 1;
      int m1 = (mt+1)*16 + l15;   if (m1 >= cnt) m1 = cnt - 1;
      int e0 = order[start + m0];
      int e1 = two ? order[start + m1] : e0;
      const unsigned short* A0 = XC + (size_t)e0*2048 + kofs + kq;
      const unsigned short* A1 = XC + (size_t)e1*2048 + kofs + kq;
      const unsigned short* Bp = &LA[l15*1032 + kq];
      f32x4 acc0 = {}, acc1 = {};
      #pragma unroll 4
      for (int kt = 0; kt < 1024; kt += 32){
        s16x8 a0 = *(const s16x8*)(A0 + kt);
        s16x8 a1 = *(const s16x8*)(A1 + kt);
        s16x8 b  = *(const s16x8*)(Bp + kt);
        acc0 = __builtin_amdgcn_mfma_f32_16x16x32_bf16(a0, b, acc0, 0, 0, 0);
        acc1 = __builtin_amdgcn_mfma_f32_16x16x32_bf16(a1, b, acc1, 0, 0, 0);
      }
      int rowb = (lane >> 4) * 4;
      #pragma unroll
      for (int i = 0; i < 4; i++){
        int m = mt*16 + rowb + i;
        if (m < cnt){
          int e = order[start + m];
          low[((size_t)g*B_ + e)*R_ + l15] = acc0[i];
        }
      }
      if (two){
        #pragma unroll
        for (int i = 0; i < 4; i++){
          int m = (mt+1)*16 + rowb + i;
          if (m < cnt){
            int e = order[start + m];
            low[((size_t)g*B_ + e)*R_ + l15] = acc1[i];
          }
        }
      }
    }
    return;
  }

  // ---- gemm path (128x128, 2-phase) ----
  int u = bx >> 7;                  // 128 blocks/unit; K=2048 units first
  int tile = bx & 127;
  int K = (u < 2) ? 2048 : 1024;
  int kofs = (u == 3) ? 1024 : 0;
  const size_t uoffs[4] = {W0OFF, W1OFF, W2OFF, W3OFF};
  const unsigned short* Wt = Wt_all + uoffs[u];
  unsigned short* Y = Yall + (size_t)u * ((size_t)B_ * F_);

  unsigned short (*As)[4096] = (unsigned short(*)[4096])smem;           // [2][128*32]
  unsigned short (*Bs)[4096] = (unsigned short(*)[4096])(smem + 8192);  // [2][128*32]

  int lane = t & 63, wave = t >> 6;
  int mt = tile >> 3, nt = tile & 7;
  int row0 = mt * 128, col0 = nt * 128;
  int wrow = (wave >> 1) * 64, wcol = (wave & 1) * 64;

  int arow = t >> 2;
  int achk = ((t & 3) ^ ((t >> 3) & 3)) * 8;   // swizzled source k-slot

  const unsigned short* Ab  = XC + (size_t)(row0 + arow) * 2048 + kofs + achk;
  const unsigned short* Ab2 = Ab + (size_t)64 * 2048;
  const unsigned short* Bb  = Wt + (size_t)(col0 + arow) * K + achk;
  const unsigned short* Bb2 = Bb + (size_t)64 * K;

  int l15 = lane & 15;
  int kof = (((lane >> 4) ^ ((l15 >> 1) & 3)) * 8);   // swizzled read slot
  f32x4 acc[4][4] = {};

  gload16(Ab,  &As[0][t*8]);  gload16(Ab2, &As[0][2048 + t*8]);
  gload16(Bb,  &Bs[0][t*8]);  gload16(Bb2, &Bs[0][2048 + t*8]);
  __syncthreads();

  int cur = 0;
  for (int kt = 32; kt < K; kt += 32){
    int nxt = cur ^ 1;
    gload16(Ab  + kt, &As[nxt][t*8]);  gload16(Ab2 + kt, &As[nxt][2048 + t*8]);
    gload16(Bb  + kt, &Bs[nxt][t*8]);  gload16(Bb2 + kt, &Bs[nxt][2048 + t*8]);
    s16x8 af[4], bfr[4];
    #pragma unroll
    for (int m = 0; m < 4; m++)
      af[m] = *(const s16x8*)&As[cur][(wrow + m*16 + l15)*32 + kof];
    #pragma unroll
    for (int n = 0; n < 4; n++)
      bfr[n] = *(const s16x8*)&Bs[cur][(wcol + n*16 + l15)*32 + kof];
    __builtin_amdgcn_s_setprio(1);
    #pragma unroll
    for (int m = 0; m < 4; m++){
      #pragma unroll
      for (int n = 0; n < 4; n++){
        acc[m][n] = __builtin_amdgcn_mfma_f32_16x16x32_bf16(af[m], bfr[n], acc[m][n], 0, 0, 0);
      }
    }
    __builtin_amdgcn_s_setprio(0);
    __syncthreads();
    cur = nxt;
  }
  {
    s16x8 af[4], bfr[4];
    #pragma unroll
    for (int m = 0; m < 4; m++)
      af[m] = *(const s16x8*)&As[cur][(wrow + m*16 + l15)*32 + kof];
    #pragma unroll
    for (int n = 0; n < 4; n++)
      bfr[n] = *(const s16x8*)&Bs[cur][(wcol + n*16 + l15)*32 + kof];
    #pragma unroll
    for (int m = 0; m < 4; m++){
      #pragma unroll
      for (int n = 0; n < 4; n++){
        acc[m][n] = __builtin_amdgcn_mfma_f32_16x16x32_bf16(af[m], bfr[n], acc[m][n], 0, 0, 0);
      }
    }
  }

  int orow = row0 + wrow + (lane >> 4) * 4;
  int ocol = col0 + wcol + l15;
  #pragma unroll
  for (int m = 0; m < 4; m++){
    #pragma unroll
    for (int n = 0; n < 4; n++){
      #pragma unroll
      for (int i = 0; i < 4; i++){
        Y[(size_t)(orow + m*16 + i) * F_ + ocol + n*16] = f2b(acc[m][n][i]);
      }
    }
  }
}

// ---------------- kernel 3: fused MFMA delta + GRU gates + output (bucketed, bf16 Y) ------
__global__ __launch_bounds__(256) void delta_final_kernel(
    const float* __restrict__ carry,
    const float* __restrict__ bias_ir, const float* __restrict__ bias_iu,
    const float* __restrict__ bias_ic,
    const float* __restrict__ lb_ir, const float* __restrict__ lb_rr,
    const float* __restrict__ lb_iu, const float* __restrict__ lb_ru,
    const float* __restrict__ lb_ic, const float* __restrict__ lb_rc,
    const int* __restrict__ starts, const int* __restrict__ order,
    const float* __restrict__ low, const unsigned short* __restrict__ Yall,
    float* __restrict__ out){
  int s = blockIdx.x;
  int c0 = blockIdx.y * 128;
  __shared__ unsigned short Bsm[3 * 128 * 40];   // 3 stacked [col][k0..31], stride 40
  int t = threadIdx.x;
  const float* lbp[6] = {lb_ir, lb_rr, lb_iu, lb_ru, lb_ic, lb_rc};
  #pragma unroll
  for (int j = 0; j < 6; j++){
    const float* lb = lbp[j] + (size_t)s * R_ * F_;
    unsigned short* Bj = &Bsm[(j >> 1)*5120 + (j & 1)*16];
    #pragma unroll
    for (int it = 0; it < 2; it++){
      int idx = t + it*256;
      int r = idx >> 5, c4 = (idx & 31) * 4;
      float4 v = *(const float4*)&lb[(size_t)r*F_ + c0 + c4];
      Bj[(c4+0)*40 + r] = f2b(v.x);
      Bj[(c4+1)*40 + r] = f2b(v.y);
      Bj[(c4+2)*40 + r] = f2b(v.z);
      Bj[(c4+3)*40 + r] = f2b(v.w);
    }
  }
  __syncthreads();
  int start = starts[s], cnt = starts[s+1] - start;
  if (cnt == 0) return;
  int lane = t & 63, wave = t >> 6;
  int l15 = lane & 15, kq = (lane >> 4) * 8;   // 0,8,16,24
  int ntiles = (cnt + 15) >> 4;
  const unsigned short* Y0 = Yall + 0*(size_t)B_*F_;
  const unsigned short* Y1 = Yall + 1*(size_t)B_*F_;
  const unsigned short* Y2 = Yall + 2*(size_t)B_*F_;
  const unsigned short* Y3 = Yall + 3*(size_t)B_*F_;
  int k8 = kq & 15; bool hi = (kq >= 16);
  for (int pt = wave; pt < ntiles*2; pt += 4){
    int mt = pt >> 1, cf0 = (pt & 1) * 4;
    int m = mt*16 + l15; if (m >= cnt) m = cnt - 1;
    int e = order[start + m];
    s16x8 a_r, a_u, a_c1 = {}, a_c2 = {};
    {
      const float* p = &low[((size_t)(hi ? 3 : 0)*B_ + e)*R_ + k8];
      float4 v0 = *(const float4*)p, v1 = *(const float4*)(p+4);
      a_r[0]=f2b(v0.x); a_r[1]=f2b(v0.y); a_r[2]=f2b(v0.z); a_r[3]=f2b(v0.w);
      a_r[4]=f2b(v1.x); a_r[5]=f2b(v1.y); a_r[6]=f2b(v1.z); a_r[7]=f2b(v1.w);
    }
    {
      const float* p = &low[((size_t)(hi ? 4 : 1)*B_ + e)*R_ + k8];
      float4 v0 = *(const float4*)p, v1 = *(const float4*)(p+4);
      a_u[0]=f2b(v0.x); a_u[1]=f2b(v0.y); a_u[2]=f2b(v0.z); a_u[3]=f2b(v0.w);
      a_u[4]=f2b(v1.x); a_u[5]=f2b(v1.y); a_u[6]=f2b(v1.z); a_u[7]=f2b(v1.w);
    }
    if (!hi){
      const float* p = &low[((size_t)2*B_ + e)*R_ + k8];
      float4 v0 = *(const float4*)p, v1 = *(const float4*)(p+4);
      a_c1[0]=f2b(v0.x); a_c1[1]=f2b(v0.y); a_c1[2]=f2b(v0.z); a_c1[3]=f2b(v0.w);
      a_c1[4]=f2b(v1.x); a_c1[5]=f2b(v1.y); a_c1[6]=f2b(v1.z); a_c1[7]=f2b(v1.w);
    } else {
      const float* p = &low[((size_t)5*B_ + e)*R_ + k8];
      float4 v0 = *(const float4*)p, v1 = *(const float4*)(p+4);
      a_c2[0]=f2b(v0.x); a_c2[1]=f2b(v0.y); a_c2[2]=f2b(v0.z); a_c2[3]=f2b(v0.w);
      a_c2[4]=f2b(v1.x); a_c2[5]=f2b(v1.y); a_c2[6]=f2b(v1.z); a_c2[7]=f2b(v1.w);
    }
    int rowb = (lane >> 4) * 4;
    int erow[4]; bool wok[4];
    #pragma unroll
    for (int i = 0; i < 4; i++){
      int mm = mt*16 + rowb + i;
      wok[i] = (mm < cnt);
      erow[i] = order[start + (wok[i] ? mm : cnt - 1)];
    }
    #pragma unroll
    for (int cf = cf0; cf < cf0 + 4; cf++){
      int col = cf*16 + l15;
      s16x8 b_r = *(const s16x8*)&Bsm[0*5120 + col*40 + kq];
      s16x8 b_u = *(const s16x8*)&Bsm[1*5120 + col*40 + kq];
      s16x8 b_c = *(const s16x8*)&Bsm[2*5120 + col*40 + kq];
      f32x4 zero = {};
      f32x4 dr  = __builtin_amdgcn_mfma_f32_16x16x32_bf16(a_r,  b_r, zero, 0, 0, 0);
      f32x4 du  = __builtin_amdgcn_mfma_f32_16x16x32_bf16(a_u,  b_u, zero, 0, 0, 0);
      f32x4 dic = __builtin_amdgcn_mfma_f32_16x16x32_bf16(a_c1, b_c, zero, 0, 0, 0);
      f32x4 drc = __builtin_amdgcn_mfma_f32_16x16x32_bf16(a_c2, b_c, zero, 0, 0, 0);
      int oc = c0 + col;
      float br = bias_ir[oc], bu = bias_iu[oc], bc = bias_ic[oc];
      #pragma unroll
      for (int i = 0; i < 4; i++){
        if (wok[i]){
          size_t idx = (size_t)erow[i]*F_ + oc;
          float zr  = b2f(Y0[idx]) + br + dr[i];
          float zu  = b2f(Y1[idx]) + bu + du[i];
          float zic = b2f(Y2[idx]) + bc + dic[i];
          float zrc = b2f(Y3[idx]) + drc[i];
          float cv  = carry[idx];
          float rr = 1.f/(1.f+__expf(-zr));
          float uu = 1.f/(1.f+__expf(-zu));
          float a = zic + rr*zrc;
          float ee = __expf(-2.f*fabsf(a));
          float cand = copysignf((1.f-ee)/(1.f+ee), a);
          out[idx] = (1.f-uu)*cand + uu*cv;
        }
      }
    }
  }
}

extern "C" void kernel_launch(void* const* d_in, const int* in_sizes, int n_in,
                              void* d_out, int out_size, void* d_ws, size_t ws_size,
                              hipStream_t stream){
  const float* carry   = (const float*)d_in[0];
  const float* x       = (const float*)d_in[1];
  const int*   ids     = (const int*)d_in[2];
  const float* w_ir    = (const float*)d_in[3];
  const float* bias_ir = (const float*)d_in[4];
  const float* la_ir   = (const float*)d_in[5];
  const float* lb_ir   = (const float*)d_in[6];
  const float* w_iu    = (const float*)d_in[7];
  const float* bias_iu = (const float*)d_in[8];
  const float* la_iu   = (const float*)d_in[9];
  const float* lb_iu   = (const float*)d_in[10];
  const float* w_ic    = (const float*)d_in[11];
  const float* bias_ic = (const float*)d_in[12];
  const float* la_ic   = (const float*)d_in[13];
  const float* lb_ic   = (const float*)d_in[14];
  const float* w_rr    = (const float*)d_in[15];
  const float* la_rr   = (const float*)d_in[16];
  const float* lb_rr   = (const float*)d_in[17];
  const float* w_ru    = (const float*)d_in[18];
  const float* la_ru   = (const float*)d_in[19];
  const float* lb_ru   = (const float*)d_in[20];
  const float* w_rc    = (const float*)d_in[21];
  const float* la_rc   = (const float*)d_in[22];
  const float* lb_rc   = (const float*)d_in[23];

  char* ws = (char*)d_ws;
  unsigned short* XC     = (unsigned short*)(ws + 0);          // 8 MiB
  unsigned short* Wt_all = (unsigned short*)(ws + 8388608);    // 12 MiB
  unsigned short* Yall   = (unsigned short*)(ws + 20971520);   // 16 MiB (4 x 4 MiB bf16)
  float* low  = (float*)(ws + 37748736);                       // 768 KiB
  int* starts = (int*)(ws + 38535168);
  int* order  = (int*)(ws + 38536192);

  prep_kernel<<<dim3(3585), dim3(256), 0, stream>>>(x, carry, XC,
                                                    w_ir, w_rr, w_iu, w_ru, w_ic, w_rc,
                                                    Wt_all, ids, starts, order);
  gemm_low_kernel<<<dim3(896), dim3(256), 0, stream>>>(XC, Wt_all, Yall,
                                                       la_ir, la_iu, la_ic,
                                                       la_rr, la_ru, la_rc,
                                                       starts, order, low);
  delta_final_kernel<<<dim3(64, 8), dim3(256), 0, stream>>>(carry, bias_ir, bias_iu, bias_ic,
                                                            lb_ir, lb_rr, lb_iu, lb_ru,
                                                            lb_ic, lb_rc,
                                                            starts, order, low, Yall,
                                                            (float*)d_out);
}